// Round 1
// 401.832 us; speedup vs baseline: 1.0521x; 1.0521x over previous
//
#include <hip/hip_runtime.h>
#include <hip/hip_bf16.h>
#include <math.h>

typedef __hip_bfloat16 bf16;
typedef short s16x8 __attribute__((ext_vector_type(8)));
typedef float f32x4 __attribute__((ext_vector_type(4)));

#define NDIM 256
#define NTG 1024
#define NT 4096

__device__ __forceinline__ float gelu_exact(float x) {
    return 0.5f * x * (1.0f + erff(x * 0.70710678118654752440f));
}
__device__ __forceinline__ float sigmoidf_(float x) {
    return 1.0f / (1.0f + __expf(-x));
}
__device__ __forceinline__ short f2bf_s(float x) {
    union { bf16 h; short s; } cv;
    cv.h = __float2bfloat16(x);
    return cv.s;
}
__device__ __forceinline__ float bf2f(short s) {
    union { bf16 h; short s; } cv;
    cv.s = s;
    return __bfloat162float(cv.h);
}

// ---------------- fused prep: gf transpose + mean partials, weight transposes,
//                  wkv bf16 cvt, qh.  blocks [0,2048): gft; [2048,2752): prep.
__global__ __launch_bounds__(256) void k_prep(
        const float* __restrict__ gf, const float* __restrict__ ipw,
        const float* __restrict__ opw, const float* __restrict__ twm,
        const float* __restrict__ pw1, const float* __restrict__ queries,
        const float* __restrict__ ipb,
        bf16* __restrict__ gfT, float* __restrict__ partial,
        float* __restrict__ opwT, float* __restrict__ twT, float* __restrict__ pw1T,
        bf16* __restrict__ wkvK, bf16* __restrict__ wkvV,
        float* __restrict__ qh) {
    __shared__ float smem[64 * 65 + 256];
    int blk = blockIdx.x, tid = threadIdx.x;
    if (blk < 2048) {
        // gf [b][c][t] -> gfT bf16 [b][t][c]  +  per-tile mean partials
        float (*tile)[65] = (float(*)[65])smem;
        float* psum = smem + 64 * 65;
        int t0 = (blk & 15) * 64, c0 = ((blk >> 4) & 3) * 64, b = blk >> 6;
        int tt = tid & 63, ci = tid >> 6;
        #pragma unroll
        for (int r = 0; r < 16; ++r) {
            int cl = ci * 16 + r;
            tile[cl][tt] = gf[((size_t)(b * 256 + c0 + cl)) * NTG + t0 + tt];
        }
        __syncthreads();
        int cc = tid & 63, ti = tid >> 6;
        #pragma unroll
        for (int r = 0; r < 16; ++r) {
            int tl = ti * 16 + r;
            gfT[((size_t)(b * 1024 + t0 + tl)) * 256 + c0 + cc] =
                __float2bfloat16(tile[cc][tl]);
        }
        float ps = 0.f;
        #pragma unroll
        for (int r = 0; r < 16; ++r) ps += tile[cc][ti * 16 + r];
        psum[tid] = ps;
        __syncthreads();
        if (tid < 64) {
            float s = psum[tid] + psum[tid + 64] + psum[tid + 128] + psum[tid + 192];
            partial[(b * 256 + c0 + tid) * 16 + (blk & 15)] = s;
        }
    } else {
        int pblk = blk - 2048;
        if (pblk < 384) {
            int id = pblk * 256 + tid;
            if (id < 65536) {
                int k = id >> 8, c = id & 255;
                opwT[id] = opw[c * 256 + k];
                twT[id]  = twm[c * 256 + k];
            } else {
                int id2 = id - 65536;
                int k = id2 >> 7, m = id2 & 127;
                pw1T[id2] = pw1[m * 256 + k];
            }
        } else if (pblk < 640) {
            int id = (pblk - 384) * 256 + tid;
            wkvK[id] = __float2bfloat16(ipw[65536 + id]);
            wkvV[id] = __float2bfloat16(ipw[131072 + id]);
        } else {
            // qh: 64 blocks
            float* qrow = smem;
            int n = pblk - 640, c = tid;
            qrow[c] = queries[n * 256 + c];
            __syncthreads();
            float s = ipb[c];
            const float* wr = ipw + c * 256;
            for (int k = 0; k < 256; ++k) s += qrow[k] * wr[k];
            qh[n * 256 + c] = s;
        }
    }
}

// ---------------- fused K/V projection (MFMA bf16) + metahs ------------------
// blocks [0,2048): kv with decode x=blk&7 (t-tile), y=(blk>>3)&7 (sel/n), b=blk>>6
// blocks [2048,2080): meta gelu + heart_shift (reads mean partials)
__global__ __launch_bounds__(256) void k_kv(
        const short* __restrict__ gfT, const short* __restrict__ wkvK,
        const short* __restrict__ wkvV, const float* __restrict__ ipb,
        const float* __restrict__ meta, const float* __restrict__ mw,
        const float* __restrict__ mb, const float* __restrict__ partial,
        const float* __restrict__ sw, const float* __restrict__ sb,
        short* __restrict__ kvh, short* __restrict__ vTg,
        float* __restrict__ metag, float* __restrict__ hshift) {
    int blk = blockIdx.x;
    int tid = threadIdx.x;
    if (blk >= 2048) {
        __shared__ float gm[256];
        int b = blk - 2048, c = tid;
        float m = 0.f;
        const float* pp = partial + (b * 256 + c) * 16;
        #pragma unroll
        for (int tt = 0; tt < 16; ++tt) m += pp[tt];
        gm[c] = m * (1.0f / 1024.0f);
        float s = mb[c];
        #pragma unroll
        for (int j = 0; j < 6; ++j) s += meta[b * 6 + j] * mw[c * 6 + j];
        metag[b * 256 + c] = gelu_exact(s);
        __syncthreads();
        if (c < 3) {
            float t = sb[c];
            for (int k = 0; k < 256; ++k) t += gm[k] * sw[c * 256 + k];
            hshift[b * 4 + c] = tanhf(t) * 0.3f;
        }
        return;
    }
    int w = tid >> 6, lane = tid & 63, lm = lane & 15, quad = lane >> 4;
    int bx = blk & 7, byq = (blk >> 3) & 7, b = blk >> 6;
    int t0 = bx * 128 + w * 32;
    int sel = byq >> 2;
    int n0 = (byq & 3) * 64;
    if (sel == 0) {
        f32x4 acc[4][2];
        #pragma unroll
        for (int ni = 0; ni < 4; ++ni)
            #pragma unroll
            for (int mt = 0; mt < 2; ++mt) acc[ni][mt] = (f32x4)(0.0f);
        #pragma unroll
        for (int ks = 0; ks < 8; ++ks) {
            int c = ks * 32 + quad * 8;
            s16x8 bg[2];
            #pragma unroll
            for (int mt = 0; mt < 2; ++mt)
                bg[mt] = *(const s16x8*)&gfT[((size_t)(b * 1024 + t0 + mt * 16 + lm)) * 256 + c];
            #pragma unroll
            for (int ni = 0; ni < 4; ++ni) {
                s16x8 aw = *(const s16x8*)&wkvK[(n0 + ni * 16 + lm) * 256 + c];
                #pragma unroll
                for (int mt = 0; mt < 2; ++mt)
                    acc[ni][mt] = __builtin_amdgcn_mfma_f32_16x16x32_bf16(aw, bg[mt], acc[ni][mt], 0, 0, 0);
            }
        }
        #pragma unroll
        for (int ni = 0; ni < 4; ++ni) {
            int nb4 = n0 + ni * 16 + quad * 4;
            float4 bias = *(const float4*)&ipb[256 + nb4];
            #pragma unroll
            for (int mt = 0; mt < 2; ++mt) {
                int t = t0 + mt * 16 + lm;
                ushort4 o;
                o.x = (unsigned short)f2bf_s(acc[ni][mt][0] + bias.x);
                o.y = (unsigned short)f2bf_s(acc[ni][mt][1] + bias.y);
                o.z = (unsigned short)f2bf_s(acc[ni][mt][2] + bias.z);
                o.w = (unsigned short)f2bf_s(acc[ni][mt][3] + bias.w);
                *(ushort4*)&kvh[((size_t)(b * 1024 + t)) * 256 + nb4] = o;
            }
        }
    } else {
        f32x4 acc[2][4];
        #pragma unroll
        for (int mt = 0; mt < 2; ++mt)
            #pragma unroll
            for (int ni = 0; ni < 4; ++ni) acc[mt][ni] = (f32x4)(0.0f);
        #pragma unroll
        for (int ks = 0; ks < 8; ++ks) {
            int c = ks * 32 + quad * 8;
            s16x8 ag[2];
            #pragma unroll
            for (int mt = 0; mt < 2; ++mt)
                ag[mt] = *(const s16x8*)&gfT[((size_t)(b * 1024 + t0 + mt * 16 + lm)) * 256 + c];
            #pragma unroll
            for (int ni = 0; ni < 4; ++ni) {
                s16x8 bw = *(const s16x8*)&wkvV[(n0 + ni * 16 + lm) * 256 + c];
                #pragma unroll
                for (int mt = 0; mt < 2; ++mt)
                    acc[mt][ni] = __builtin_amdgcn_mfma_f32_16x16x32_bf16(ag[mt], bw, acc[mt][ni], 0, 0, 0);
            }
        }
        #pragma unroll
        for (int ni = 0; ni < 4; ++ni) {
            int nv = n0 + ni * 16 + lm;
            float bias = ipb[512 + nv];
            #pragma unroll
            for (int mt = 0; mt < 2; ++mt) {
                int t4 = t0 + mt * 16 + quad * 4;
                ushort4 o;
                o.x = (unsigned short)f2bf_s(acc[mt][ni][0] + bias);
                o.y = (unsigned short)f2bf_s(acc[mt][ni][1] + bias);
                o.z = (unsigned short)f2bf_s(acc[mt][ni][2] + bias);
                o.w = (unsigned short)f2bf_s(acc[mt][ni][3] + bias);
                *(ushort4*)&vTg[((size_t)(b * 256 + nv)) * 1024 + t4] = o;
            }
        }
    }
}

// ---------------- MFMA attention: grid (half, h, b), 4 waves x 128 keys ------
__global__ __launch_bounds__(256) void k_attn(
        const short* __restrict__ kvh, const short* __restrict__ vTg,
        const float* __restrict__ qh,
        float* __restrict__ o_half, float* __restrict__ l_half) {
    __shared__ short pT[4][64 * 40];
    __shared__ float obuf[4][64 * 36];
    __shared__ float lbuf[4 * 64];
    int tid = threadIdx.x;
    int w = tid >> 6, lane = tid & 63, lm = lane & 15, quad = lane >> 4;
    int half = blockIdx.x, h = blockIdx.y, b = blockIdx.z;
    s16x8 aq[4];
    #pragma unroll
    for (int mt = 0; mt < 4; ++mt) {
        const float* qp = qh + (mt * 16 + lm) * 256 + h * 32 + quad * 8;
        #pragma unroll
        for (int j = 0; j < 8; ++j) aq[mt][j] = f2bf_s(qp[j]);
    }
    f32x4 acco[2][4];
    #pragma unroll
    for (int dt = 0; dt < 2; ++dt)
        #pragma unroll
        for (int qt = 0; qt < 4; ++qt) acco[dt][qt] = (f32x4)(0.0f);
    float lp[4][4];
    #pragma unroll
    for (int mt = 0; mt < 4; ++mt)
        #pragma unroll
        for (int r = 0; r < 4; ++r) lp[mt][r] = 0.f;
    const float scale = 0.17677669529663687f;   // 1/sqrt(32)
    int kb = half * 512 + w * 128;
    for (int ch = 0; ch < 4; ++ch) {
        int n0 = kb + ch * 32;
        #pragma unroll
        for (int nt = 0; nt < 2; ++nt) {
            int key = n0 + nt * 16 + lm;
            s16x8 bk = *(const s16x8*)&kvh[((size_t)(b * 1024 + key)) * 256 + h * 32 + quad * 8];
            f32x4 zero = {0.f, 0.f, 0.f, 0.f};
            #pragma unroll
            for (int mt = 0; mt < 4; ++mt) {
                f32x4 S = __builtin_amdgcn_mfma_f32_16x16x32_bf16(aq[mt], bk, zero, 0, 0, 0);
                #pragma unroll
                for (int r = 0; r < 4; ++r) {
                    float e = __expf(S[r] * scale);
                    lp[mt][r] += e;
                    pT[w][(mt * 16 + quad * 4 + r) * 40 + nt * 16 + lm] = f2bf_s(e);
                }
            }
        }
        s16x8 av[2], bp[4];
        #pragma unroll
        for (int dt = 0; dt < 2; ++dt)
            av[dt] = *(const s16x8*)&vTg[((size_t)(b * 256 + h * 32 + dt * 16 + lm)) * 1024 + n0 + quad * 8];
        #pragma unroll
        for (int qt = 0; qt < 4; ++qt)
            bp[qt] = *(const s16x8*)&pT[w][(qt * 16 + lm) * 40 + quad * 8];
        #pragma unroll
        for (int dt = 0; dt < 2; ++dt)
            #pragma unroll
            for (int qt = 0; qt < 4; ++qt)
                acco[dt][qt] = __builtin_amdgcn_mfma_f32_16x16x32_bf16(av[dt], bp[qt], acco[dt][qt], 0, 0, 0);
    }
    #pragma unroll
    for (int mt = 0; mt < 4; ++mt)
        #pragma unroll
        for (int r = 0; r < 4; ++r) {
            float v = lp[mt][r];
            v += __shfl_xor(v, 1); v += __shfl_xor(v, 2);
            v += __shfl_xor(v, 4); v += __shfl_xor(v, 8);
            lp[mt][r] = v;
        }
    #pragma unroll
    for (int dt = 0; dt < 2; ++dt)
        #pragma unroll
        for (int qt = 0; qt < 4; ++qt) {
            int q = qt * 16 + lm;
            float4 t;
            t.x = acco[dt][qt][0]; t.y = acco[dt][qt][1];
            t.z = acco[dt][qt][2]; t.w = acco[dt][qt][3];
            *(float4*)&obuf[w][q * 36 + dt * 16 + quad * 4] = t;
        }
    if (lm == 0) {
        #pragma unroll
        for (int mt = 0; mt < 4; ++mt)
            #pragma unroll
            for (int r = 0; r < 4; ++r)
                lbuf[w * 64 + mt * 16 + quad * 4 + r] = lp[mt][r];
    }
    __syncthreads();
    int q = tid & 63, dg = tid >> 6;
    int blk = (b * 8 + h) * 2 + half;
    float l = lbuf[q] + lbuf[64 + q] + lbuf[128 + q] + lbuf[192 + q];
    float o[8];
    #pragma unroll
    for (int j = 0; j < 8; ++j) o[j] = 0.f;
    #pragma unroll
    for (int w2 = 0; w2 < 4; ++w2) {
        const float* src = &obuf[w2][q * 36 + dg * 8];
        #pragma unroll
        for (int j = 0; j < 8; ++j) o[j] += src[j];
    }
    float* dst = &o_half[(((size_t)blk * 64) + q) * 32 + dg * 8];
    #pragma unroll
    for (int j = 0; j < 8; ++j) dst[j] = o[j];
    if (dg == 0) l_half[blk * 64 + q] = l;
}

// ---------------- out_proj + LN + meta + tw(bf16) + phase MLP + geometry -----
// 4 queries per block, grid (16, 32): 2 blocks/CU for latency hiding.
__global__ __launch_bounds__(256) void k_post(
        const float* __restrict__ o_half, const float* __restrict__ l_half,
        const float* __restrict__ queries,
        const float* __restrict__ opwT, const float* __restrict__ opb,
        const float* __restrict__ lng, const float* __restrict__ lnb,
        const float* __restrict__ metag, const float* __restrict__ hshift,
        const float* __restrict__ twT, const float* __restrict__ tbv,
        const float* __restrict__ pw1T, const float* __restrict__ pb1,
        const float* __restrict__ pw2, const float* __restrict__ pb2,
        const float* __restrict__ p0a,
        bf16* __restrict__ twbf, float* __restrict__ out_amp,
        float* __restrict__ out_ppos, float* __restrict__ out_dip,
        float* __restrict__ out_vol) {
    __shared__ float cs[4][256];
    __shared__ float xs[4][256];
    __shared__ float qs[4][256];
    __shared__ float h1[4][128];
    __shared__ float ps[4][10];
    int tid = threadIdx.x;
    int n0 = blockIdx.x * 4, b = blockIdx.y;
    {
        int h = tid >> 5, d = tid & 31;
        int blk0 = (b * 8 + h) * 2;
        #pragma unroll
        for (int r = 0; r < 4; ++r) {
            int q = n0 + r;
            float l = l_half[blk0 * 64 + q] + l_half[(blk0 + 1) * 64 + q];
            float v0 = o_half[(((size_t)blk0 * 64) + q) * 32 + d];
            float v1 = o_half[(((size_t)(blk0 + 1) * 64) + q) * 32 + d];
            cs[r][tid] = (v0 + v1) / l;
        }
    }
    __syncthreads();
    {
        int c = tid;
        float a[4];
        #pragma unroll
        for (int nn = 0; nn < 4; ++nn) a[nn] = opb[c];
        for (int k = 0; k < 256; ++k) {
            float w = opwT[k * 256 + c];
            #pragma unroll
            for (int nn = 0; nn < 4; ++nn) a[nn] += cs[nn][k] * w;
        }
        #pragma unroll
        for (int nn = 0; nn < 4; ++nn)
            xs[nn][c] = queries[(n0 + nn) * 256 + c] + a[nn];
    }
    __syncthreads();
    {
        int w = tid >> 6, lane = tid & 63;
        int nr = w;
        float x0 = xs[nr][lane], x1 = xs[nr][lane + 64],
              x2 = xs[nr][lane + 128], x3 = xs[nr][lane + 192];
        float s = x0 + x1 + x2 + x3;
        #pragma unroll
        for (int off = 32; off >= 1; off >>= 1) s += __shfl_xor(s, off);
        float mu = s * (1.0f / 256.0f);
        float e0 = x0 - mu, e1 = x1 - mu, e2 = x2 - mu, e3 = x3 - mu;
        float v = e0*e0 + e1*e1 + e2*e2 + e3*e3;
        #pragma unroll
        for (int off = 32; off >= 1; off >>= 1) v += __shfl_xor(v, off);
        float rstd = 1.0f / sqrtf(v * (1.0f / 256.0f) + 1e-5f);
        #pragma unroll
        for (int j = 0; j < 4; ++j) {
            int c = lane + 64 * j;
            qs[nr][c] = (xs[nr][c] - mu) * rstd * lng[c] + lnb[c] + metag[b * 256 + c];
        }
    }
    __syncthreads();
    {
        int c = tid;
        float a[4];
        #pragma unroll
        for (int nn = 0; nn < 4; ++nn) a[nn] = tbv[c];
        for (int k = 0; k < 256; ++k) {
            float w = twT[k * 256 + c];
            #pragma unroll
            for (int nn = 0; nn < 4; ++nn) a[nn] += qs[nn][k] * w;
        }
        #pragma unroll
        for (int nn = 0; nn < 4; ++nn)
            twbf[(size_t)(b * 64 + n0 + nn) * 256 + c] = __float2bfloat16(a[nn]);
    }
    {
        int m = tid & 127, g = tid >> 7;
        float a[2];
        #pragma unroll
        for (int q2 = 0; q2 < 2; ++q2) a[q2] = pb1[m];
        for (int k = 0; k < 256; ++k) {
            float w = pw1T[k * 128 + m];
            #pragma unroll
            for (int q2 = 0; q2 < 2; ++q2) a[q2] += qs[g * 2 + q2][k] * w;
        }
        #pragma unroll
        for (int q2 = 0; q2 < 2; ++q2) h1[g * 2 + q2][m] = gelu_exact(a[q2]);
    }
    __syncthreads();
    if (tid < 40) {
        int nr = tid / 10, j = tid % 10;
        float s = pb2[j];
        for (int m = 0; m < 128; ++m) s += h1[nr][m] * pw2[j * 128 + m];
        ps[nr][j] = s;
    }
    __syncthreads();
    if (tid < 4) {
        int nr = tid;
        int gn = b * 64 + n0 + nr;
        #pragma unroll
        for (int j = 0; j < 3; ++j) {
            float delta = tanhf(ps[nr][j]) * 0.2f;
            out_ppos[gn * 3 + j] = p0a[(n0 + nr) * 3 + j] + delta + hshift[b * 4 + j];
        }
        float d0 = ps[nr][3], d1 = ps[nr][4], d2 = ps[nr][5];
        float dn = fmaxf(sqrtf(d0 * d0 + d1 * d1 + d2 * d2), 1e-6f);
        out_dip[gn * 3 + 0] = d0 / dn;
        out_dip[gn * 3 + 1] = d1 / dn;
        out_dip[gn * 3 + 2] = d2 / dn;
        #pragma unroll
        for (int j = 0; j < 3; ++j)
            out_vol[gn * 3 + j] = sigmoidf_(ps[nr][6 + j]) * 0.5f + 0.001f;
        out_amp[gn] = sigmoidf_(ps[nr][9]) + 0.0001f;
    }
}

// ---------------- temporal logits via MFMA bf16 (double-buffered staging) ----
__global__ __launch_bounds__(256) void k_temporal(
        const float* __restrict__ lf, const short* __restrict__ twbf,
        short* __restrict__ logits) {
    __shared__ __align__(16) short tws[64 * 264];
    __shared__ __align__(16) short lfs[2][32 * 132];
    int tid = threadIdx.x;
    int t0 = blockIdx.x * 128, b = blockIdx.y;
    int wave = tid >> 6, lane = tid & 63;
    int lm = lane & 15, quad = lane >> 4;

    #pragma unroll
    for (int i = 0; i < 8; ++i) {
        int id = i * 256 + tid;
        int n = id >> 5, c8 = id & 31;
        s16x8 v = *(const s16x8*)&twbf[(size_t)(b * 64 + n) * 256 + c8 * 8];
        *(s16x8*)&tws[n * 264 + c8 * 8] = v;
    }

    float4 fr[4];
    // prologue: stage ksi = 0 into lfs[0]
    #pragma unroll
    for (int r = 0; r < 4; ++r) {
        int id = r * 256 + tid;
        int c = id >> 5, t4 = id & 31;
        fr[r] = *(const float4*)&lf[((size_t)(b * 256 + c)) * 4096 + t0 + t4 * 4];
    }
    #pragma unroll
    for (int r = 0; r < 4; ++r) {
        int id = r * 256 + tid;
        int c = id >> 5, t4 = id & 31;
        ushort4 o;
        o.x = (unsigned short)f2bf_s(fr[r].x);
        o.y = (unsigned short)f2bf_s(fr[r].y);
        o.z = (unsigned short)f2bf_s(fr[r].z);
        o.w = (unsigned short)f2bf_s(fr[r].w);
        *(ushort4*)&lfs[0][c * 132 + t4 * 4] = o;
    }

    f32x4 acc[2][4];
    #pragma unroll
    for (int mi = 0; mi < 2; ++mi)
        #pragma unroll
        for (int ni = 0; ni < 4; ++ni) acc[mi][ni] = (f32x4)(0.0f);

    __syncthreads();

    for (int ksi = 0; ksi < 8; ++ksi) {
        int cur = ksi & 1;
        if (ksi < 7) {
            // issue next tile's global loads early (hide under MFMA)
            int c0n = (ksi + 1) * 32;
            #pragma unroll
            for (int r = 0; r < 4; ++r) {
                int id = r * 256 + tid;
                int c = id >> 5, t4 = id & 31;
                fr[r] = *(const float4*)&lf[((size_t)(b * 256 + c0n + c)) * 4096 + t0 + t4 * 4];
            }
        }
        int c0 = ksi * 32;
        #pragma unroll
        for (int mi = 0; mi < 2; ++mi) {
            int tl = wave * 32 + mi * 16 + lm;
            s16x8 af;
            #pragma unroll
            for (int j = 0; j < 8; ++j)
                af[j] = lfs[cur][(quad * 8 + j) * 132 + tl];
            #pragma unroll
            for (int ni = 0; ni < 4; ++ni) {
                s16x8 bfr = *(const s16x8*)&tws[(ni * 16 + lm) * 264 + c0 + quad * 8];
                acc[mi][ni] = __builtin_amdgcn_mfma_f32_16x16x32_bf16(af, bfr, acc[mi][ni], 0, 0, 0);
            }
        }
        if (ksi < 7) {
            #pragma unroll
            for (int r = 0; r < 4; ++r) {
                int id = r * 256 + tid;
                int c = id >> 5, t4 = id & 31;
                ushort4 o;
                o.x = (unsigned short)f2bf_s(fr[r].x);
                o.y = (unsigned short)f2bf_s(fr[r].y);
                o.z = (unsigned short)f2bf_s(fr[r].z);
                o.w = (unsigned short)f2bf_s(fr[r].w);
                *(ushort4*)&lfs[cur ^ 1][c * 132 + t4 * 4] = o;
            }
        }
        __syncthreads();
    }
    #pragma unroll
    for (int mi = 0; mi < 2; ++mi) {
        #pragma unroll
        for (int ni = 0; ni < 4; ++ni) {
            int n = ni * 16 + lm;
            int t = t0 + wave * 32 + mi * 16 + quad * 4;
            ushort4 o;
            o.x = (unsigned short)f2bf_s(acc[mi][ni][0] * 0.0625f);
            o.y = (unsigned short)f2bf_s(acc[mi][ni][1] * 0.0625f);
            o.z = (unsigned short)f2bf_s(acc[mi][ni][2] * 0.0625f);
            o.w = (unsigned short)f2bf_s(acc[mi][ni][3] * 0.0625f);
            *(ushort4*)&logits[(size_t)(b * 64 + n) * 4096 + t] = o;
        }
    }
}

// ---------------- warped sampling + sigmoid envelope (+ inline delay) --------
__global__ void k_envelope(const short* __restrict__ logits,
                           const float* __restrict__ out_amp,
                           const float* __restrict__ out_ppos,
                           const float* __restrict__ wds,
                           const float* __restrict__ ebp,
                           float* __restrict__ env) {
    int blk = blockIdx.x;
    int bn = blk >> 2, seg = blk & 3;
    int b = bn >> 6, n = bn & 63;
    int tid = threadIdx.x;
    int lane = tid & 63;
    // inline delay computation (redundant per wave)
    float v = out_amp[b * 64 + lane];
    int idx = lane;
    #pragma unroll
    for (int off = 1; off < 64; off <<= 1) {
        float ov = __shfl_xor(v, off);
        int oi = __shfl_xor(idx, off);
        if (ov > v || (ov == v && oi < idx)) { v = ov; idx = oi; }
    }
    float dx = out_ppos[(b * 64 + n) * 3 + 0] - out_ppos[(b * 64 + idx) * 3 + 0];
    float dy = out_ppos[(b * 64 + n) * 3 + 1] - out_ppos[(b * 64 + idx) * 3 + 1];
    float dz = out_ppos[(b * 64 + n) * 3 + 2] - out_ppos[(b * 64 + idx) * 3 + 2];
    float dist = sqrtf(dx * dx + dy * dy + dz * dz);
    float sp = log1pf(expf(wds[0]));
    float dl = fminf(fmaxf(sp * dist, 0.f), 0.1f);
    float eb = ebp[0];
    const short* gl = logits + (size_t)bn * 4096;
    int t_base = seg * 1024 + tid * 4;
    float ov4[4];
    #pragma unroll
    for (int u = 0; u < 4; ++u) {
        int t = t_base + u;
        float xb = fmaf((float)t, 2.0f / 4095.0f, -1.0f);
        float xp = (xb - dl + 1.0f) * 2047.5f;
        float x0f = floorf(xp);
        int x0 = (int)x0f;
        float w1 = xp - x0f, w0 = 1.0f - w1;
        float g0 = (x0 >= 0 && x0 <= 4095) ? bf2f(gl[x0]) : 0.f;
        int x1 = x0 + 1;
        float g1 = (x1 >= 0 && x1 <= 4095) ? bf2f(gl[x1]) : 0.f;
        float sh = w0 * g0 + w1 * g1;
        ov4[u] = 1.0f / (1.0f + __expf(-(sh + eb)));
    }
    float4 o; o.x = ov4[0]; o.y = ov4[1]; o.z = ov4[2]; o.w = ov4[3];
    *reinterpret_cast<float4*>(&env[(size_t)bn * 4096 + t_base]) = o;
}

extern "C" void kernel_launch(void* const* d_in, const int* in_sizes, int n_in,
                              void* d_out, int out_size, void* d_ws, size_t ws_size,
                              hipStream_t stream) {
    const float* lf   = (const float*)d_in[0];
    const float* gf   = (const float*)d_in[1];
    const float* meta = (const float*)d_in[2];
    const float* qrs  = (const float*)d_in[3];
    const float* p0a  = (const float*)d_in[4];
    const float* ipw  = (const float*)d_in[5];
    const float* ipb  = (const float*)d_in[6];
    const float* opw  = (const float*)d_in[7];
    const float* opb  = (const float*)d_in[8];
    const float* lng  = (const float*)d_in[9];
    const float* lnb  = (const float*)d_in[10];
    const float* mw   = (const float*)d_in[11];
    const float* mb   = (const float*)d_in[12];
    const float* twm  = (const float*)d_in[13];
    const float* tbv  = (const float*)d_in[14];
    const float* sw   = (const float*)d_in[15];
    const float* sb   = (const float*)d_in[16];
    const float* pw1  = (const float*)d_in[17];
    const float* pb1  = (const float*)d_in[18];
    const float* pw2  = (const float*)d_in[19];
    const float* pb2  = (const float*)d_in[20];
    const float* wds  = (const float*)d_in[21];
    const float* ebp  = (const float*)d_in[22];

    char* ws = (char*)d_ws;
    short* kvh    = (short*)(ws);                    // 16,777,216  K bf16 [b][t][256]
    short* vTg    = (short*)(ws + 16777216);         // 16,777,216  V^T bf16 [b][n][1024]
    short* gfT    = (short*)(ws + 33554432);         // 16,777,216  bf16 [b][t][c]
    short* logits = (short*)(ws + 50331648);         // 16,777,216  bf16 [b*n][4096]
    float* o_half = (float*)(ws + 67108864);         //  4,194,304
    float* l_half = (float*)(ws + 71303168);         //    131,072
    short* twbf   = (short*)(ws + 71434240);         //  1,048,576
    float* qh     = (float*)(ws + 72482816);         //     65,536
    float* metag  = (float*)(ws + 72581120);         //     32,768
    float* hshift = (float*)(ws + 72613888);         //        512
    float* opwT   = (float*)(ws + 72614400);         //    262,144
    float* twT    = (float*)(ws + 72876544);         //    262,144
    float* pw1T   = (float*)(ws + 73138688);         //    131,072
    short* wkvK   = (short*)(ws + 73269760);         //    131,072
    short* wkvV   = (short*)(ws + 73400832);         //    131,072
    float* partial= (float*)(ws + 73531904);         //    524,288  [b][c][16] mean partials

    float* out_amp  = (float*)d_out;
    float* out_ppos = out_amp + 2048;
    float* out_dip  = out_amp + 8192;
    float* out_vol  = out_amp + 14336;
    float* env      = out_amp + 20480;

    k_prep<<<2752, 256, 0, stream>>>(gf, ipw, opw, twm, pw1, qrs, ipb,
                                     (bf16*)gfT, partial, opwT, twT, pw1T,
                                     (bf16*)wkvK, (bf16*)wkvV, qh);
    k_kv<<<2080, 256, 0, stream>>>(gfT, wkvK, wkvV, ipb, meta, mw, mb, partial,
                                   sw, sb, kvh, vTg, metag, hshift);
    k_attn<<<dim3(2, 8, 32), 256, 0, stream>>>(kvh, vTg, qh, o_half, l_half);
    k_post<<<dim3(16, 32), 256, 0, stream>>>(o_half, l_half, qrs, opwT, opb, lng, lnb,
                                             metag, hshift, twT, tbv, pw1T, pb1, pw2, pb2,
                                             p0a, (bf16*)twbf, out_amp, out_ppos,
                                             out_dip, out_vol);
    k_temporal<<<dim3(32, 32), 256, 0, stream>>>(lf, twbf, logits);
    k_envelope<<<8192, 256, 0, stream>>>(logits, out_amp, out_ppos, wds, ebp, env);
}

// Round 2
// 389.043 us; speedup vs baseline: 1.0867x; 1.0329x over previous
//
#include <hip/hip_runtime.h>
#include <hip/hip_bf16.h>
#include <math.h>

typedef __hip_bfloat16 bf16;
typedef short s16x8 __attribute__((ext_vector_type(8)));
typedef float f32x4 __attribute__((ext_vector_type(4)));

#define NDIM 256
#define NTG 1024
#define NT 4096

__device__ __forceinline__ float gelu_exact(float x) {
    return 0.5f * x * (1.0f + erff(x * 0.70710678118654752440f));
}
__device__ __forceinline__ float sigmoidf_(float x) {
    return 1.0f / (1.0f + __expf(-x));
}
__device__ __forceinline__ short f2bf_s(float x) {
    union { bf16 h; short s; } cv;
    cv.h = __float2bfloat16(x);
    return cv.s;
}
__device__ __forceinline__ float bf2f(short s) {
    union { bf16 h; short s; } cv;
    cv.s = s;
    return __bfloat162float(cv.h);
}

// ---------------- fused prep: gf transpose + mean partials, weight transposes,
//                  wkv bf16 cvt, qh.  blocks [0,2048): gft; [2048,2752): prep.
__global__ __launch_bounds__(256) void k_prep(
        const float* __restrict__ gf, const float* __restrict__ ipw,
        const float* __restrict__ opw, const float* __restrict__ twm,
        const float* __restrict__ pw1, const float* __restrict__ queries,
        const float* __restrict__ ipb,
        bf16* __restrict__ gfT, float* __restrict__ partial,
        float* __restrict__ opwT, float* __restrict__ twT, float* __restrict__ pw1T,
        bf16* __restrict__ wkvK, bf16* __restrict__ wkvV,
        float* __restrict__ qh) {
    __shared__ float smem[64 * 65 + 256];
    int blk = blockIdx.x, tid = threadIdx.x;
    if (blk < 2048) {
        // gf [b][c][t] -> gfT bf16 [b][t][c]  +  per-tile mean partials
        float (*tile)[65] = (float(*)[65])smem;
        float* psum = smem + 64 * 65;
        int t0 = (blk & 15) * 64, c0 = ((blk >> 4) & 3) * 64, b = blk >> 6;
        int tt = tid & 63, ci = tid >> 6;
        #pragma unroll
        for (int r = 0; r < 16; ++r) {
            int cl = ci * 16 + r;
            tile[cl][tt] = gf[((size_t)(b * 256 + c0 + cl)) * NTG + t0 + tt];
        }
        __syncthreads();
        int cc = tid & 63, ti = tid >> 6;
        #pragma unroll
        for (int r = 0; r < 16; ++r) {
            int tl = ti * 16 + r;
            gfT[((size_t)(b * 1024 + t0 + tl)) * 256 + c0 + cc] =
                __float2bfloat16(tile[cc][tl]);
        }
        float ps = 0.f;
        #pragma unroll
        for (int r = 0; r < 16; ++r) ps += tile[cc][ti * 16 + r];
        psum[tid] = ps;
        __syncthreads();
        if (tid < 64) {
            float s = psum[tid] + psum[tid + 64] + psum[tid + 128] + psum[tid + 192];
            partial[(b * 256 + c0 + tid) * 16 + (blk & 15)] = s;
        }
    } else {
        int pblk = blk - 2048;
        if (pblk < 384) {
            int id = pblk * 256 + tid;
            if (id < 65536) {
                int k = id >> 8, c = id & 255;
                opwT[id] = opw[c * 256 + k];
                twT[id]  = twm[c * 256 + k];
            } else {
                int id2 = id - 65536;
                int k = id2 >> 7, m = id2 & 127;
                pw1T[id2] = pw1[m * 256 + k];
            }
        } else if (pblk < 640) {
            int id = (pblk - 384) * 256 + tid;
            wkvK[id] = __float2bfloat16(ipw[65536 + id]);
            wkvV[id] = __float2bfloat16(ipw[131072 + id]);
        } else {
            // qh: 64 blocks
            float* qrow = smem;
            int n = pblk - 640, c = tid;
            qrow[c] = queries[n * 256 + c];
            __syncthreads();
            float s = ipb[c];
            const float* wr = ipw + c * 256;
            for (int k = 0; k < 256; ++k) s += qrow[k] * wr[k];
            qh[n * 256 + c] = s;
        }
    }
}

// ---------------- fused K/V projection (MFMA bf16) + metahs ------------------
// blocks [0,512): kv. decode: bx=blk&7 (t-tile of 128), sel=(blk>>3)&1, b=blk>>4.
//   Each block covers ALL n (4 x n0-tiles of 64) for its sel: gfT fragments are
//   hoisted to VGPRs once (read 1x instead of 4x).
// blocks [512,544): meta gelu + heart_shift (reads mean partials)
__global__ __launch_bounds__(256) void k_kv(
        const short* __restrict__ gfT, const short* __restrict__ wkvK,
        const short* __restrict__ wkvV, const float* __restrict__ ipb,
        const float* __restrict__ meta, const float* __restrict__ mw,
        const float* __restrict__ mb, const float* __restrict__ partial,
        const float* __restrict__ sw, const float* __restrict__ sb,
        short* __restrict__ kvh, short* __restrict__ vTg,
        float* __restrict__ metag, float* __restrict__ hshift) {
    int blk = blockIdx.x;
    int tid = threadIdx.x;
    if (blk >= 512) {
        __shared__ float gm[256];
        int b = blk - 512, c = tid;
        float m = 0.f;
        const float* pp = partial + (b * 256 + c) * 16;
        #pragma unroll
        for (int tt = 0; tt < 16; ++tt) m += pp[tt];
        gm[c] = m * (1.0f / 1024.0f);
        float s = mb[c];
        #pragma unroll
        for (int j = 0; j < 6; ++j) s += meta[b * 6 + j] * mw[c * 6 + j];
        metag[b * 256 + c] = gelu_exact(s);
        __syncthreads();
        if (c < 3) {
            float t = sb[c];
            for (int k = 0; k < 256; ++k) t += gm[k] * sw[c * 256 + k];
            hshift[b * 4 + c] = tanhf(t) * 0.3f;
        }
        return;
    }
    int w = tid >> 6, lane = tid & 63, lm = lane & 15, quad = lane >> 4;
    int bx = blk & 7, sel = (blk >> 3) & 1, b = blk >> 4;
    int t0 = bx * 128 + w * 32;
    // hoist gfT fragments: 8 k-steps x 2 m-tiles (64 VGPRs)
    s16x8 g[8][2];
    #pragma unroll
    for (int ks = 0; ks < 8; ++ks) {
        int c = ks * 32 + quad * 8;
        #pragma unroll
        for (int mt = 0; mt < 2; ++mt)
            g[ks][mt] = *(const s16x8*)&gfT[((size_t)(b * 1024 + t0 + mt * 16 + lm)) * 256 + c];
    }
    if (sel == 0) {
        for (int n0i = 0; n0i < 4; ++n0i) {
            int n0 = n0i * 64;
            f32x4 acc[4][2];
            #pragma unroll
            for (int ni = 0; ni < 4; ++ni)
                #pragma unroll
                for (int mt = 0; mt < 2; ++mt) acc[ni][mt] = (f32x4)(0.0f);
            #pragma unroll
            for (int ks = 0; ks < 8; ++ks) {
                int c = ks * 32 + quad * 8;
                #pragma unroll
                for (int ni = 0; ni < 4; ++ni) {
                    s16x8 aw = *(const s16x8*)&wkvK[(n0 + ni * 16 + lm) * 256 + c];
                    #pragma unroll
                    for (int mt = 0; mt < 2; ++mt)
                        acc[ni][mt] = __builtin_amdgcn_mfma_f32_16x16x32_bf16(aw, g[ks][mt], acc[ni][mt], 0, 0, 0);
                }
            }
            #pragma unroll
            for (int ni = 0; ni < 4; ++ni) {
                int nb4 = n0 + ni * 16 + quad * 4;
                float4 bias = *(const float4*)&ipb[256 + nb4];
                #pragma unroll
                for (int mt = 0; mt < 2; ++mt) {
                    int t = t0 + mt * 16 + lm;
                    ushort4 o;
                    o.x = (unsigned short)f2bf_s(acc[ni][mt][0] + bias.x);
                    o.y = (unsigned short)f2bf_s(acc[ni][mt][1] + bias.y);
                    o.z = (unsigned short)f2bf_s(acc[ni][mt][2] + bias.z);
                    o.w = (unsigned short)f2bf_s(acc[ni][mt][3] + bias.w);
                    *(ushort4*)&kvh[((size_t)(b * 1024 + t)) * 256 + nb4] = o;
                }
            }
        }
    } else {
        for (int n0i = 0; n0i < 4; ++n0i) {
            int n0 = n0i * 64;
            f32x4 acc[2][4];
            #pragma unroll
            for (int mt = 0; mt < 2; ++mt)
                #pragma unroll
                for (int ni = 0; ni < 4; ++ni) acc[mt][ni] = (f32x4)(0.0f);
            #pragma unroll
            for (int ks = 0; ks < 8; ++ks) {
                int c = ks * 32 + quad * 8;
                #pragma unroll
                for (int ni = 0; ni < 4; ++ni) {
                    s16x8 bw = *(const s16x8*)&wkvV[(n0 + ni * 16 + lm) * 256 + c];
                    #pragma unroll
                    for (int mt = 0; mt < 2; ++mt)
                        acc[mt][ni] = __builtin_amdgcn_mfma_f32_16x16x32_bf16(g[ks][mt], bw, acc[mt][ni], 0, 0, 0);
                }
            }
            #pragma unroll
            for (int ni = 0; ni < 4; ++ni) {
                int nv = n0 + ni * 16 + lm;
                float bias = ipb[512 + nv];
                #pragma unroll
                for (int mt = 0; mt < 2; ++mt) {
                    int t4 = t0 + mt * 16 + quad * 4;
                    ushort4 o;
                    o.x = (unsigned short)f2bf_s(acc[mt][ni][0] + bias);
                    o.y = (unsigned short)f2bf_s(acc[mt][ni][1] + bias);
                    o.z = (unsigned short)f2bf_s(acc[mt][ni][2] + bias);
                    o.w = (unsigned short)f2bf_s(acc[mt][ni][3] + bias);
                    *(ushort4*)&vTg[((size_t)(b * 256 + nv)) * 1024 + t4] = o;
                }
            }
        }
    }
}

// ---------------- MFMA attention: grid (half, h, b), 4 waves x 128 keys ------
__global__ __launch_bounds__(256) void k_attn(
        const short* __restrict__ kvh, const short* __restrict__ vTg,
        const float* __restrict__ qh,
        float* __restrict__ o_half, float* __restrict__ l_half) {
    __shared__ short pT[4][64 * 40];
    __shared__ float obuf[4][64 * 36];
    __shared__ float lbuf[4 * 64];
    int tid = threadIdx.x;
    int w = tid >> 6, lane = tid & 63, lm = lane & 15, quad = lane >> 4;
    int half = blockIdx.x, h = blockIdx.y, b = blockIdx.z;
    s16x8 aq[4];
    #pragma unroll
    for (int mt = 0; mt < 4; ++mt) {
        const float4* qp = (const float4*)(qh + (mt * 16 + lm) * 256 + h * 32 + quad * 8);
        float4 qa = qp[0], qb = qp[1];
        aq[mt][0] = f2bf_s(qa.x); aq[mt][1] = f2bf_s(qa.y);
        aq[mt][2] = f2bf_s(qa.z); aq[mt][3] = f2bf_s(qa.w);
        aq[mt][4] = f2bf_s(qb.x); aq[mt][5] = f2bf_s(qb.y);
        aq[mt][6] = f2bf_s(qb.z); aq[mt][7] = f2bf_s(qb.w);
    }
    f32x4 acco[2][4];
    #pragma unroll
    for (int dt = 0; dt < 2; ++dt)
        #pragma unroll
        for (int qt = 0; qt < 4; ++qt) acco[dt][qt] = (f32x4)(0.0f);
    float lp[4][4];
    #pragma unroll
    for (int mt = 0; mt < 4; ++mt)
        #pragma unroll
        for (int r = 0; r < 4; ++r) lp[mt][r] = 0.f;
    const float scale = 0.17677669529663687f;   // 1/sqrt(32)
    int kb = half * 512 + w * 128;
    for (int ch = 0; ch < 4; ++ch) {
        int n0 = kb + ch * 32;
        #pragma unroll
        for (int nt = 0; nt < 2; ++nt) {
            int key = n0 + nt * 16 + lm;
            s16x8 bk = *(const s16x8*)&kvh[((size_t)(b * 1024 + key)) * 256 + h * 32 + quad * 8];
            f32x4 zero = {0.f, 0.f, 0.f, 0.f};
            #pragma unroll
            for (int mt = 0; mt < 4; ++mt) {
                f32x4 S = __builtin_amdgcn_mfma_f32_16x16x32_bf16(aq[mt], bk, zero, 0, 0, 0);
                #pragma unroll
                for (int r = 0; r < 4; ++r) {
                    float e = __expf(S[r] * scale);
                    lp[mt][r] += e;
                    pT[w][(mt * 16 + quad * 4 + r) * 40 + nt * 16 + lm] = f2bf_s(e);
                }
            }
        }
        s16x8 av[2], bp[4];
        #pragma unroll
        for (int dt = 0; dt < 2; ++dt)
            av[dt] = *(const s16x8*)&vTg[((size_t)(b * 256 + h * 32 + dt * 16 + lm)) * 1024 + n0 + quad * 8];
        #pragma unroll
        for (int qt = 0; qt < 4; ++qt)
            bp[qt] = *(const s16x8*)&pT[w][(qt * 16 + lm) * 40 + quad * 8];
        #pragma unroll
        for (int dt = 0; dt < 2; ++dt)
            #pragma unroll
            for (int qt = 0; qt < 4; ++qt)
                acco[dt][qt] = __builtin_amdgcn_mfma_f32_16x16x32_bf16(av[dt], bp[qt], acco[dt][qt], 0, 0, 0);
    }
    #pragma unroll
    for (int mt = 0; mt < 4; ++mt)
        #pragma unroll
        for (int r = 0; r < 4; ++r) {
            float v = lp[mt][r];
            v += __shfl_xor(v, 1); v += __shfl_xor(v, 2);
            v += __shfl_xor(v, 4); v += __shfl_xor(v, 8);
            lp[mt][r] = v;
        }
    #pragma unroll
    for (int dt = 0; dt < 2; ++dt)
        #pragma unroll
        for (int qt = 0; qt < 4; ++qt) {
            int q = qt * 16 + lm;
            float4 t;
            t.x = acco[dt][qt][0]; t.y = acco[dt][qt][1];
            t.z = acco[dt][qt][2]; t.w = acco[dt][qt][3];
            *(float4*)&obuf[w][q * 36 + dt * 16 + quad * 4] = t;
        }
    if (lm == 0) {
        #pragma unroll
        for (int mt = 0; mt < 4; ++mt)
            #pragma unroll
            for (int r = 0; r < 4; ++r)
                lbuf[w * 64 + mt * 16 + quad * 4 + r] = lp[mt][r];
    }
    __syncthreads();
    int q = tid & 63, dg = tid >> 6;
    int blk = (b * 8 + h) * 2 + half;
    float l = lbuf[q] + lbuf[64 + q] + lbuf[128 + q] + lbuf[192 + q];
    float o[8];
    #pragma unroll
    for (int j = 0; j < 8; ++j) o[j] = 0.f;
    #pragma unroll
    for (int w2 = 0; w2 < 4; ++w2) {
        const float* src = &obuf[w2][q * 36 + dg * 8];
        #pragma unroll
        for (int j = 0; j < 8; ++j) o[j] += src[j];
    }
    float* dst = &o_half[(((size_t)blk * 64) + q) * 32 + dg * 8];
    #pragma unroll
    for (int j = 0; j < 8; ++j) dst[j] = o[j];
    if (dg == 0) l_half[blk * 64 + q] = l;
}

// ---------------- out_proj + LN + meta + tw(bf16) + phase MLP + geometry -----
// 4 queries per block, grid (16, 32): 2 blocks/CU for latency hiding.
__global__ __launch_bounds__(256) void k_post(
        const float* __restrict__ o_half, const float* __restrict__ l_half,
        const float* __restrict__ queries,
        const float* __restrict__ opwT, const float* __restrict__ opb,
        const float* __restrict__ lng, const float* __restrict__ lnb,
        const float* __restrict__ metag, const float* __restrict__ hshift,
        const float* __restrict__ twT, const float* __restrict__ tbv,
        const float* __restrict__ pw1T, const float* __restrict__ pb1,
        const float* __restrict__ pw2, const float* __restrict__ pb2,
        const float* __restrict__ p0a,
        bf16* __restrict__ twbf, float* __restrict__ out_amp,
        float* __restrict__ out_ppos, float* __restrict__ out_dip,
        float* __restrict__ out_vol) {
    __shared__ float cs[4][256];
    __shared__ float xs[4][256];
    __shared__ float qs[4][256];
    __shared__ float h1[4][128];
    __shared__ float ps[4][10];
    int tid = threadIdx.x;
    int n0 = blockIdx.x * 4, b = blockIdx.y;
    {
        int h = tid >> 5, d = tid & 31;
        int blk0 = (b * 8 + h) * 2;
        #pragma unroll
        for (int r = 0; r < 4; ++r) {
            int q = n0 + r;
            float l = l_half[blk0 * 64 + q] + l_half[(blk0 + 1) * 64 + q];
            float v0 = o_half[(((size_t)blk0 * 64) + q) * 32 + d];
            float v1 = o_half[(((size_t)(blk0 + 1) * 64) + q) * 32 + d];
            cs[r][tid] = (v0 + v1) / l;
        }
    }
    __syncthreads();
    {
        int c = tid;
        float a[4];
        #pragma unroll
        for (int nn = 0; nn < 4; ++nn) a[nn] = opb[c];
        for (int k = 0; k < 256; ++k) {
            float w = opwT[k * 256 + c];
            #pragma unroll
            for (int nn = 0; nn < 4; ++nn) a[nn] += cs[nn][k] * w;
        }
        #pragma unroll
        for (int nn = 0; nn < 4; ++nn)
            xs[nn][c] = queries[(n0 + nn) * 256 + c] + a[nn];
    }
    __syncthreads();
    {
        int w = tid >> 6, lane = tid & 63;
        int nr = w;
        float x0 = xs[nr][lane], x1 = xs[nr][lane + 64],
              x2 = xs[nr][lane + 128], x3 = xs[nr][lane + 192];
        float s = x0 + x1 + x2 + x3;
        #pragma unroll
        for (int off = 32; off >= 1; off >>= 1) s += __shfl_xor(s, off);
        float mu = s * (1.0f / 256.0f);
        float e0 = x0 - mu, e1 = x1 - mu, e2 = x2 - mu, e3 = x3 - mu;
        float v = e0*e0 + e1*e1 + e2*e2 + e3*e3;
        #pragma unroll
        for (int off = 32; off >= 1; off >>= 1) v += __shfl_xor(v, off);
        float rstd = 1.0f / sqrtf(v * (1.0f / 256.0f) + 1e-5f);
        #pragma unroll
        for (int j = 0; j < 4; ++j) {
            int c = lane + 64 * j;
            qs[nr][c] = (xs[nr][c] - mu) * rstd * lng[c] + lnb[c] + metag[b * 256 + c];
        }
    }
    __syncthreads();
    {
        int c = tid;
        float a[4];
        #pragma unroll
        for (int nn = 0; nn < 4; ++nn) a[nn] = tbv[c];
        for (int k = 0; k < 256; ++k) {
            float w = twT[k * 256 + c];
            #pragma unroll
            for (int nn = 0; nn < 4; ++nn) a[nn] += qs[nn][k] * w;
        }
        #pragma unroll
        for (int nn = 0; nn < 4; ++nn)
            twbf[(size_t)(b * 64 + n0 + nn) * 256 + c] = __float2bfloat16(a[nn]);
    }
    {
        int m = tid & 127, g = tid >> 7;
        float a[2];
        #pragma unroll
        for (int q2 = 0; q2 < 2; ++q2) a[q2] = pb1[m];
        for (int k = 0; k < 256; ++k) {
            float w = pw1T[k * 128 + m];
            #pragma unroll
            for (int q2 = 0; q2 < 2; ++q2) a[q2] += qs[g * 2 + q2][k] * w;
        }
        #pragma unroll
        for (int q2 = 0; q2 < 2; ++q2) h1[g * 2 + q2][m] = gelu_exact(a[q2]);
    }
    __syncthreads();
    if (tid < 40) {
        int nr = tid / 10, j = tid % 10;
        float s = pb2[j];
        for (int m = 0; m < 128; ++m) s += h1[nr][m] * pw2[j * 128 + m];
        ps[nr][j] = s;
    }
    __syncthreads();
    if (tid < 4) {
        int nr = tid;
        int gn = b * 64 + n0 + nr;
        #pragma unroll
        for (int j = 0; j < 3; ++j) {
            float delta = tanhf(ps[nr][j]) * 0.2f;
            out_ppos[gn * 3 + j] = p0a[(n0 + nr) * 3 + j] + delta + hshift[b * 4 + j];
        }
        float d0 = ps[nr][3], d1 = ps[nr][4], d2 = ps[nr][5];
        float dn = fmaxf(sqrtf(d0 * d0 + d1 * d1 + d2 * d2), 1e-6f);
        out_dip[gn * 3 + 0] = d0 / dn;
        out_dip[gn * 3 + 1] = d1 / dn;
        out_dip[gn * 3 + 2] = d2 / dn;
        #pragma unroll
        for (int j = 0; j < 3; ++j)
            out_vol[gn * 3 + j] = sigmoidf_(ps[nr][6 + j]) * 0.5f + 0.001f;
        out_amp[gn] = sigmoidf_(ps[nr][9]) + 0.0001f;
    }
}

// ---------------- temporal logits via MFMA bf16 (double-buffered staging) ----
__global__ __launch_bounds__(256) void k_temporal(
        const float* __restrict__ lf, const short* __restrict__ twbf,
        short* __restrict__ logits) {
    __shared__ __align__(16) short tws[64 * 264];
    __shared__ __align__(16) short lfs[2][32 * 132];
    int tid = threadIdx.x;
    int t0 = blockIdx.x * 128, b = blockIdx.y;
    int wave = tid >> 6, lane = tid & 63;
    int lm = lane & 15, quad = lane >> 4;

    #pragma unroll
    for (int i = 0; i < 8; ++i) {
        int id = i * 256 + tid;
        int n = id >> 5, c8 = id & 31;
        s16x8 v = *(const s16x8*)&twbf[(size_t)(b * 64 + n) * 256 + c8 * 8];
        *(s16x8*)&tws[n * 264 + c8 * 8] = v;
    }

    float4 fr[4];
    // prologue: stage ksi = 0 into lfs[0]
    #pragma unroll
    for (int r = 0; r < 4; ++r) {
        int id = r * 256 + tid;
        int c = id >> 5, t4 = id & 31;
        fr[r] = *(const float4*)&lf[((size_t)(b * 256 + c)) * 4096 + t0 + t4 * 4];
    }
    #pragma unroll
    for (int r = 0; r < 4; ++r) {
        int id = r * 256 + tid;
        int c = id >> 5, t4 = id & 31;
        ushort4 o;
        o.x = (unsigned short)f2bf_s(fr[r].x);
        o.y = (unsigned short)f2bf_s(fr[r].y);
        o.z = (unsigned short)f2bf_s(fr[r].z);
        o.w = (unsigned short)f2bf_s(fr[r].w);
        *(ushort4*)&lfs[0][c * 132 + t4 * 4] = o;
    }

    f32x4 acc[2][4];
    #pragma unroll
    for (int mi = 0; mi < 2; ++mi)
        #pragma unroll
        for (int ni = 0; ni < 4; ++ni) acc[mi][ni] = (f32x4)(0.0f);

    __syncthreads();

    for (int ksi = 0; ksi < 8; ++ksi) {
        int cur = ksi & 1;
        if (ksi < 7) {
            // issue next tile's global loads early (hide under MFMA)
            int c0n = (ksi + 1) * 32;
            #pragma unroll
            for (int r = 0; r < 4; ++r) {
                int id = r * 256 + tid;
                int c = id >> 5, t4 = id & 31;
                fr[r] = *(const float4*)&lf[((size_t)(b * 256 + c0n + c)) * 4096 + t0 + t4 * 4];
            }
        }
        int c0 = ksi * 32;
        #pragma unroll
        for (int mi = 0; mi < 2; ++mi) {
            int tl = wave * 32 + mi * 16 + lm;
            s16x8 af;
            #pragma unroll
            for (int j = 0; j < 8; ++j)
                af[j] = lfs[cur][(quad * 8 + j) * 132 + tl];
            #pragma unroll
            for (int ni = 0; ni < 4; ++ni) {
                s16x8 bfr = *(const s16x8*)&tws[(ni * 16 + lm) * 264 + c0 + quad * 8];
                acc[mi][ni] = __builtin_amdgcn_mfma_f32_16x16x32_bf16(af, bfr, acc[mi][ni], 0, 0, 0);
            }
        }
        if (ksi < 7) {
            #pragma unroll
            for (int r = 0; r < 4; ++r) {
                int id = r * 256 + tid;
                int c = id >> 5, t4 = id & 31;
                ushort4 o;
                o.x = (unsigned short)f2bf_s(fr[r].x);
                o.y = (unsigned short)f2bf_s(fr[r].y);
                o.z = (unsigned short)f2bf_s(fr[r].z);
                o.w = (unsigned short)f2bf_s(fr[r].w);
                *(ushort4*)&lfs[cur ^ 1][c * 132 + t4 * 4] = o;
            }
        }
        __syncthreads();
    }
    #pragma unroll
    for (int mi = 0; mi < 2; ++mi) {
        #pragma unroll
        for (int ni = 0; ni < 4; ++ni) {
            int n = ni * 16 + lm;
            int t = t0 + wave * 32 + mi * 16 + quad * 4;
            ushort4 o;
            o.x = (unsigned short)f2bf_s(acc[mi][ni][0] * 0.0625f);
            o.y = (unsigned short)f2bf_s(acc[mi][ni][1] * 0.0625f);
            o.z = (unsigned short)f2bf_s(acc[mi][ni][2] * 0.0625f);
            o.w = (unsigned short)f2bf_s(acc[mi][ni][3] * 0.0625f);
            *(ushort4*)&logits[(size_t)(b * 64 + n) * 4096 + t] = o;
        }
    }
}

// ---------------- warped sampling + sigmoid envelope (LDS-staged, branchless)
// one block per (b,n): stage 4096 logits + zero pads into LDS, then 16 t/thread.
__global__ __launch_bounds__(256) void k_envelope(
        const short* __restrict__ logits,
        const float* __restrict__ out_amp,
        const float* __restrict__ out_ppos,
        const float* __restrict__ wds,
        const float* __restrict__ ebp,
        float* __restrict__ env) {
    __shared__ __align__(16) short ls[208 + 4096 + 16];
    int bn = blockIdx.x;
    int b = bn >> 6, n = bn & 63;
    int tid = threadIdx.x;
    int lane = tid & 63;
    // zero pads (left 208 for max shift ~205, right 16 for x1 overrun)
    if (tid < 208) ls[tid] = 0;
    if (tid < 16) ls[208 + 4096 + tid] = 0;
    // stage logits row coalesced: 16 shorts per thread
    const short* gl = logits + (size_t)bn * 4096;
    {
        s16x8 v0 = *(const s16x8*)&gl[tid * 16];
        s16x8 v1 = *(const s16x8*)&gl[tid * 16 + 8];
        *(s16x8*)&ls[208 + tid * 16] = v0;
        *(s16x8*)&ls[208 + tid * 16 + 8] = v1;
    }
    // inline delay computation (redundant per wave)
    float v = out_amp[b * 64 + lane];
    int idx = lane;
    #pragma unroll
    for (int off = 1; off < 64; off <<= 1) {
        float ov = __shfl_xor(v, off);
        int oi = __shfl_xor(idx, off);
        if (ov > v || (ov == v && oi < idx)) { v = ov; idx = oi; }
    }
    float dx = out_ppos[(b * 64 + n) * 3 + 0] - out_ppos[(b * 64 + idx) * 3 + 0];
    float dy = out_ppos[(b * 64 + n) * 3 + 1] - out_ppos[(b * 64 + idx) * 3 + 1];
    float dz = out_ppos[(b * 64 + n) * 3 + 2] - out_ppos[(b * 64 + idx) * 3 + 2];
    float dist = sqrtf(dx * dx + dy * dy + dz * dz);
    float sp = log1pf(expf(wds[0]));
    float dl = fminf(fmaxf(sp * dist, 0.f), 0.1f);
    float eb = ebp[0];
    __syncthreads();
    #pragma unroll
    for (int g = 0; g < 4; ++g) {
        int t_base = g * 1024 + tid * 4;
        float ov4[4];
        #pragma unroll
        for (int u = 0; u < 4; ++u) {
            int t = t_base + u;
            float xb = fmaf((float)t, 2.0f / 4095.0f, -1.0f);
            float xp = (xb - dl + 1.0f) * 2047.5f;
            float x0f = floorf(xp);
            int x0 = (int)x0f;
            float w1 = xp - x0f, w0 = 1.0f - w1;
            float g0 = bf2f(ls[208 + x0]);
            float g1 = bf2f(ls[208 + x0 + 1]);
            float sh = w0 * g0 + w1 * g1;
            ov4[u] = 1.0f / (1.0f + __expf(-(sh + eb)));
        }
        float4 o; o.x = ov4[0]; o.y = ov4[1]; o.z = ov4[2]; o.w = ov4[3];
        *reinterpret_cast<float4*>(&env[(size_t)bn * 4096 + t_base]) = o;
    }
}

extern "C" void kernel_launch(void* const* d_in, const int* in_sizes, int n_in,
                              void* d_out, int out_size, void* d_ws, size_t ws_size,
                              hipStream_t stream) {
    const float* lf   = (const float*)d_in[0];
    const float* gf   = (const float*)d_in[1];
    const float* meta = (const float*)d_in[2];
    const float* qrs  = (const float*)d_in[3];
    const float* p0a  = (const float*)d_in[4];
    const float* ipw  = (const float*)d_in[5];
    const float* ipb  = (const float*)d_in[6];
    const float* opw  = (const float*)d_in[7];
    const float* opb  = (const float*)d_in[8];
    const float* lng  = (const float*)d_in[9];
    const float* lnb  = (const float*)d_in[10];
    const float* mw   = (const float*)d_in[11];
    const float* mb   = (const float*)d_in[12];
    const float* twm  = (const float*)d_in[13];
    const float* tbv  = (const float*)d_in[14];
    const float* sw   = (const float*)d_in[15];
    const float* sb   = (const float*)d_in[16];
    const float* pw1  = (const float*)d_in[17];
    const float* pb1  = (const float*)d_in[18];
    const float* pw2  = (const float*)d_in[19];
    const float* pb2  = (const float*)d_in[20];
    const float* wds  = (const float*)d_in[21];
    const float* ebp  = (const float*)d_in[22];

    char* ws = (char*)d_ws;
    short* kvh    = (short*)(ws);                    // 16,777,216  K bf16 [b][t][256]
    short* vTg    = (short*)(ws + 16777216);         // 16,777,216  V^T bf16 [b][n][1024]
    short* gfT    = (short*)(ws + 33554432);         // 16,777,216  bf16 [b][t][c]
    short* logits = (short*)(ws + 50331648);         // 16,777,216  bf16 [b*n][4096]
    float* o_half = (float*)(ws + 67108864);         //  4,194,304
    float* l_half = (float*)(ws + 71303168);         //    131,072
    short* twbf   = (short*)(ws + 71434240);         //  1,048,576
    float* qh     = (float*)(ws + 72482816);         //     65,536
    float* metag  = (float*)(ws + 72581120);         //     32,768
    float* hshift = (float*)(ws + 72613888);         //        512
    float* opwT   = (float*)(ws + 72614400);         //    262,144
    float* twT    = (float*)(ws + 72876544);         //    262,144
    float* pw1T   = (float*)(ws + 73138688);         //    131,072
    short* wkvK   = (short*)(ws + 73269760);         //    131,072
    short* wkvV   = (short*)(ws + 73400832);         //    131,072
    float* partial= (float*)(ws + 73531904);         //    524,288  [b][c][16] mean partials

    float* out_amp  = (float*)d_out;
    float* out_ppos = out_amp + 2048;
    float* out_dip  = out_amp + 8192;
    float* out_vol  = out_amp + 14336;
    float* env      = out_amp + 20480;

    k_prep<<<2752, 256, 0, stream>>>(gf, ipw, opw, twm, pw1, qrs, ipb,
                                     (bf16*)gfT, partial, opwT, twT, pw1T,
                                     (bf16*)wkvK, (bf16*)wkvV, qh);
    k_kv<<<544, 256, 0, stream>>>(gfT, wkvK, wkvV, ipb, meta, mw, mb, partial,
                                  sw, sb, kvh, vTg, metag, hshift);
    k_attn<<<dim3(2, 8, 32), 256, 0, stream>>>(kvh, vTg, qh, o_half, l_half);
    k_post<<<dim3(16, 32), 256, 0, stream>>>(o_half, l_half, qrs, opwT, opb, lng, lnb,
                                             metag, hshift, twT, tbv, pw1T, pb1, pw2, pb2,
                                             p0a, (bf16*)twbf, out_amp, out_ppos,
                                             out_dip, out_vol);
    k_temporal<<<dim3(32, 32), 256, 0, stream>>>(lf, twbf, logits);
    k_envelope<<<2048, 256, 0, stream>>>(logits, out_amp, out_ppos, wds, ebp, env);
}

// Round 3
// 371.613 us; speedup vs baseline: 1.1376x; 1.0469x over previous
//
#include <hip/hip_runtime.h>
#include <hip/hip_bf16.h>
#include <math.h>

typedef __hip_bfloat16 bf16;
typedef short s16x8 __attribute__((ext_vector_type(8)));
typedef float f32x4 __attribute__((ext_vector_type(4)));

#define NDIM 256
#define NTG 1024
#define NT 4096

__device__ __forceinline__ float gelu_exact(float x) {
    return 0.5f * x * (1.0f + erff(x * 0.70710678118654752440f));
}
__device__ __forceinline__ float sigmoidf_(float x) {
    return 1.0f / (1.0f + __expf(-x));
}
__device__ __forceinline__ short f2bf_s(float x) {
    union { bf16 h; short s; } cv;
    cv.h = __float2bfloat16(x);
    return cv.s;
}
__device__ __forceinline__ float bf2f(short s) {
    union { bf16 h; short s; } cv;
    cv.s = s;
    return __bfloat162float(cv.h);
}

// ---------------- prep: weight transposes + wkv bf16 cvt + qh ----------------
// blocks [0,384): transposes; [384,640): wkv cvt; [640,704): qh.
__global__ __launch_bounds__(256) void k_prep(
        const float* __restrict__ ipw, const float* __restrict__ opw,
        const float* __restrict__ twm, const float* __restrict__ pw1,
        const float* __restrict__ queries, const float* __restrict__ ipb,
        float* __restrict__ opwT, float* __restrict__ twT, float* __restrict__ pw1T,
        bf16* __restrict__ wkvK, bf16* __restrict__ wkvV,
        float* __restrict__ qh) {
    __shared__ float qrow[256];
    int blk = blockIdx.x, tid = threadIdx.x;
    if (blk < 384) {
        int id = blk * 256 + tid;
        if (id < 65536) {
            int k = id >> 8, c = id & 255;
            opwT[id] = opw[c * 256 + k];
            twT[id]  = twm[c * 256 + k];
        } else {
            int id2 = id - 65536;
            int k = id2 >> 7, m = id2 & 127;
            pw1T[id2] = pw1[m * 256 + k];
        }
    } else if (blk < 640) {
        int id = (blk - 384) * 256 + tid;
        wkvK[id] = __float2bfloat16(ipw[65536 + id]);
        wkvV[id] = __float2bfloat16(ipw[131072 + id]);
    } else {
        int n = blk - 640, c = tid;
        qrow[c] = queries[n * 256 + c];
        __syncthreads();
        float s = ipb[c];
        const float* wr = ipw + c * 256;
        for (int k = 0; k < 256; ++k) s += qrow[k] * wr[k];
        qh[n * 256 + c] = s;
    }
}

// ---------------- fused gf-stage + K/V projection (MFMA bf16) ----------------
// 512 blocks: (b = blk>>4, tt = blk&15), t-tile of 64. Each block:
//  1. stage gf[b][:, t0:t0+64] -> LDS bf16 [64t][264c] (transpose-on-write),
//     computing gmean partials in-flight (no gfT round-trip, no atomics).
//  2. wave w owns n0 = w*64 for all 64 t  -> per-wave weight reads cut 4x.
__global__ __launch_bounds__(256) void k_kv(
        const float* __restrict__ gf, const short* __restrict__ wkvK,
        const short* __restrict__ wkvV, const float* __restrict__ ipb,
        short* __restrict__ kvh, short* __restrict__ vTg,
        float* __restrict__ partial) {
    __shared__ __align__(16) short gfs[64 * 264];
    int blk = blockIdx.x, tid = threadIdx.x;
    int b = blk >> 4, tt = blk & 15;
    int t0 = tt * 64;
    int f4 = tid & 15, grp = tid >> 4;
    // ---- stage + partial sums ----
    #pragma unroll 4
    for (int p = 0; p < 16; ++p) {
        int row = p * 16 + grp;   // channel
        float4 v = *(const float4*)&gf[((size_t)(b * 256 + row)) * 1024 + t0 + f4 * 4];
        gfs[(f4 * 4 + 0) * 264 + row] = f2bf_s(v.x);
        gfs[(f4 * 4 + 1) * 264 + row] = f2bf_s(v.y);
        gfs[(f4 * 4 + 2) * 264 + row] = f2bf_s(v.z);
        gfs[(f4 * 4 + 3) * 264 + row] = f2bf_s(v.w);
        float ps = v.x + v.y + v.z + v.w;
        ps += __shfl_xor(ps, 1); ps += __shfl_xor(ps, 2);
        ps += __shfl_xor(ps, 4); ps += __shfl_xor(ps, 8);
        if (f4 == 0) partial[(b * 256 + row) * 16 + tt] = ps;
    }
    __syncthreads();
    // ---- MFMA phase ----
    int w = tid >> 6, lane = tid & 63, lm = lane & 15, quad = lane >> 4;
    int n0 = w * 64;
    f32x4 acc[4][4];
    // K: acc[ni][mt]
    #pragma unroll
    for (int ni = 0; ni < 4; ++ni)
        #pragma unroll
        for (int mt = 0; mt < 4; ++mt) acc[ni][mt] = (f32x4)(0.0f);
    #pragma unroll
    for (int ks = 0; ks < 8; ++ks) {
        int c = ks * 32 + quad * 8;
        s16x8 gm[4];
        #pragma unroll
        for (int mt = 0; mt < 4; ++mt)
            gm[mt] = *(const s16x8*)&gfs[(mt * 16 + lm) * 264 + c];
        #pragma unroll
        for (int ni = 0; ni < 4; ++ni) {
            s16x8 aw = *(const s16x8*)&wkvK[(n0 + ni * 16 + lm) * 256 + c];
            #pragma unroll
            for (int mt = 0; mt < 4; ++mt)
                acc[ni][mt] = __builtin_amdgcn_mfma_f32_16x16x32_bf16(aw, gm[mt], acc[ni][mt], 0, 0, 0);
        }
    }
    #pragma unroll
    for (int ni = 0; ni < 4; ++ni) {
        int nb4 = n0 + ni * 16 + quad * 4;
        float4 bias = *(const float4*)&ipb[256 + nb4];
        #pragma unroll
        for (int mt = 0; mt < 4; ++mt) {
            int t = t0 + mt * 16 + lm;
            ushort4 o;
            o.x = (unsigned short)f2bf_s(acc[ni][mt][0] + bias.x);
            o.y = (unsigned short)f2bf_s(acc[ni][mt][1] + bias.y);
            o.z = (unsigned short)f2bf_s(acc[ni][mt][2] + bias.z);
            o.w = (unsigned short)f2bf_s(acc[ni][mt][3] + bias.w);
            *(ushort4*)&kvh[((size_t)(b * 1024 + t)) * 256 + nb4] = o;
        }
    }
    // V: acc[mt][ni]
    #pragma unroll
    for (int mt = 0; mt < 4; ++mt)
        #pragma unroll
        for (int ni = 0; ni < 4; ++ni) acc[mt][ni] = (f32x4)(0.0f);
    #pragma unroll
    for (int ks = 0; ks < 8; ++ks) {
        int c = ks * 32 + quad * 8;
        s16x8 gm[4];
        #pragma unroll
        for (int mt = 0; mt < 4; ++mt)
            gm[mt] = *(const s16x8*)&gfs[(mt * 16 + lm) * 264 + c];
        #pragma unroll
        for (int ni = 0; ni < 4; ++ni) {
            s16x8 bw = *(const s16x8*)&wkvV[(n0 + ni * 16 + lm) * 256 + c];
            #pragma unroll
            for (int mt = 0; mt < 4; ++mt)
                acc[mt][ni] = __builtin_amdgcn_mfma_f32_16x16x32_bf16(gm[mt], bw, acc[mt][ni], 0, 0, 0);
        }
    }
    #pragma unroll
    for (int ni = 0; ni < 4; ++ni) {
        int nv = n0 + ni * 16 + lm;
        float bias = ipb[512 + nv];
        #pragma unroll
        for (int mt = 0; mt < 4; ++mt) {
            int t4 = t0 + mt * 16 + quad * 4;
            ushort4 o;
            o.x = (unsigned short)f2bf_s(acc[mt][ni][0] + bias);
            o.y = (unsigned short)f2bf_s(acc[mt][ni][1] + bias);
            o.z = (unsigned short)f2bf_s(acc[mt][ni][2] + bias);
            o.w = (unsigned short)f2bf_s(acc[mt][ni][3] + bias);
            *(ushort4*)&vTg[((size_t)(b * 256 + nv)) * 1024 + t4] = o;
        }
    }
}

// ---------------- MFMA attention (+ metahs on z>=32) -------------------------
// grid (2, 8, 34): z<32 attention; z in {32,33}: metahs for b=(z-32)*16+y*2+x.
__global__ __launch_bounds__(256) void k_attn(
        const short* __restrict__ kvh, const short* __restrict__ vTg,
        const float* __restrict__ qh,
        const float* __restrict__ meta, const float* __restrict__ mw,
        const float* __restrict__ mb, const float* __restrict__ partial,
        const float* __restrict__ sw, const float* __restrict__ sb,
        float* __restrict__ o_half, float* __restrict__ l_half,
        float* __restrict__ metag, float* __restrict__ hshift) {
    __shared__ short pT[4][64 * 40];
    __shared__ float obuf[4][64 * 36];
    __shared__ float lbuf[4 * 64];
    if (blockIdx.z >= 32) {
        int b = (blockIdx.z - 32) * 16 + blockIdx.y * 2 + blockIdx.x;
        int c = threadIdx.x;
        float m = 0.f;
        const float* pp = partial + (b * 256 + c) * 16;
        #pragma unroll
        for (int t = 0; t < 16; ++t) m += pp[t];
        lbuf[c] = m * (1.0f / 1024.0f);
        float s = mb[c];
        #pragma unroll
        for (int j = 0; j < 6; ++j) s += meta[b * 6 + j] * mw[c * 6 + j];
        metag[b * 256 + c] = gelu_exact(s);
        __syncthreads();
        if (c < 3) {
            float t = sb[c];
            for (int k = 0; k < 256; ++k) t += lbuf[k] * sw[c * 256 + k];
            hshift[b * 4 + c] = tanhf(t) * 0.3f;
        }
        return;
    }
    int tid = threadIdx.x;
    int w = tid >> 6, lane = tid & 63, lm = lane & 15, quad = lane >> 4;
    int half = blockIdx.x, h = blockIdx.y, b = blockIdx.z;
    s16x8 aq[4];
    #pragma unroll
    for (int mt = 0; mt < 4; ++mt) {
        const float4* qp = (const float4*)(qh + (mt * 16 + lm) * 256 + h * 32 + quad * 8);
        float4 qa = qp[0], qb = qp[1];
        aq[mt][0] = f2bf_s(qa.x); aq[mt][1] = f2bf_s(qa.y);
        aq[mt][2] = f2bf_s(qa.z); aq[mt][3] = f2bf_s(qa.w);
        aq[mt][4] = f2bf_s(qb.x); aq[mt][5] = f2bf_s(qb.y);
        aq[mt][6] = f2bf_s(qb.z); aq[mt][7] = f2bf_s(qb.w);
    }
    f32x4 acco[2][4];
    #pragma unroll
    for (int dt = 0; dt < 2; ++dt)
        #pragma unroll
        for (int qt = 0; qt < 4; ++qt) acco[dt][qt] = (f32x4)(0.0f);
    float lp[4][4];
    #pragma unroll
    for (int mt = 0; mt < 4; ++mt)
        #pragma unroll
        for (int r = 0; r < 4; ++r) lp[mt][r] = 0.f;
    const float scale = 0.17677669529663687f;   // 1/sqrt(32)
    int kb = half * 512 + w * 128;
    for (int ch = 0; ch < 4; ++ch) {
        int n0 = kb + ch * 32;
        #pragma unroll
        for (int nt = 0; nt < 2; ++nt) {
            int key = n0 + nt * 16 + lm;
            s16x8 bk = *(const s16x8*)&kvh[((size_t)(b * 1024 + key)) * 256 + h * 32 + quad * 8];
            f32x4 zero = {0.f, 0.f, 0.f, 0.f};
            #pragma unroll
            for (int mt = 0; mt < 4; ++mt) {
                f32x4 S = __builtin_amdgcn_mfma_f32_16x16x32_bf16(aq[mt], bk, zero, 0, 0, 0);
                #pragma unroll
                for (int r = 0; r < 4; ++r) {
                    float e = __expf(S[r] * scale);
                    lp[mt][r] += e;
                    pT[w][(mt * 16 + quad * 4 + r) * 40 + nt * 16 + lm] = f2bf_s(e);
                }
            }
        }
        s16x8 av[2], bp[4];
        #pragma unroll
        for (int dt = 0; dt < 2; ++dt)
            av[dt] = *(const s16x8*)&vTg[((size_t)(b * 256 + h * 32 + dt * 16 + lm)) * 1024 + n0 + quad * 8];
        #pragma unroll
        for (int qt = 0; qt < 4; ++qt)
            bp[qt] = *(const s16x8*)&pT[w][(qt * 16 + lm) * 40 + quad * 8];
        #pragma unroll
        for (int dt = 0; dt < 2; ++dt)
            #pragma unroll
            for (int qt = 0; qt < 4; ++qt)
                acco[dt][qt] = __builtin_amdgcn_mfma_f32_16x16x32_bf16(av[dt], bp[qt], acco[dt][qt], 0, 0, 0);
    }
    #pragma unroll
    for (int mt = 0; mt < 4; ++mt)
        #pragma unroll
        for (int r = 0; r < 4; ++r) {
            float v = lp[mt][r];
            v += __shfl_xor(v, 1); v += __shfl_xor(v, 2);
            v += __shfl_xor(v, 4); v += __shfl_xor(v, 8);
            lp[mt][r] = v;
        }
    #pragma unroll
    for (int dt = 0; dt < 2; ++dt)
        #pragma unroll
        for (int qt = 0; qt < 4; ++qt) {
            int q = qt * 16 + lm;
            float4 t;
            t.x = acco[dt][qt][0]; t.y = acco[dt][qt][1];
            t.z = acco[dt][qt][2]; t.w = acco[dt][qt][3];
            *(float4*)&obuf[w][q * 36 + dt * 16 + quad * 4] = t;
        }
    if (lm == 0) {
        #pragma unroll
        for (int mt = 0; mt < 4; ++mt)
            #pragma unroll
            for (int r = 0; r < 4; ++r)
                lbuf[w * 64 + mt * 16 + quad * 4 + r] = lp[mt][r];
    }
    __syncthreads();
    int q = tid & 63, dg = tid >> 6;
    int blk = (b * 8 + h) * 2 + half;
    float l = lbuf[q] + lbuf[64 + q] + lbuf[128 + q] + lbuf[192 + q];
    float o[8];
    #pragma unroll
    for (int j = 0; j < 8; ++j) o[j] = 0.f;
    #pragma unroll
    for (int w2 = 0; w2 < 4; ++w2) {
        const float* src = &obuf[w2][q * 36 + dg * 8];
        #pragma unroll
        for (int j = 0; j < 8; ++j) o[j] += src[j];
    }
    float* dst = &o_half[(((size_t)blk * 64) + q) * 32 + dg * 8];
    #pragma unroll
    for (int j = 0; j < 8; ++j) dst[j] = o[j];
    if (dg == 0) l_half[blk * 64 + q] = l;
}

// ---------------- out_proj + LN + meta + tw(bf16) + phase MLP + geometry -----
// 4 queries per block, grid (16, 32): 2 blocks/CU for latency hiding.
__global__ __launch_bounds__(256) void k_post(
        const float* __restrict__ o_half, const float* __restrict__ l_half,
        const float* __restrict__ queries,
        const float* __restrict__ opwT, const float* __restrict__ opb,
        const float* __restrict__ lng, const float* __restrict__ lnb,
        const float* __restrict__ metag, const float* __restrict__ hshift,
        const float* __restrict__ twT, const float* __restrict__ tbv,
        const float* __restrict__ pw1T, const float* __restrict__ pb1,
        const float* __restrict__ pw2, const float* __restrict__ pb2,
        const float* __restrict__ p0a,
        bf16* __restrict__ twbf, float* __restrict__ out_amp,
        float* __restrict__ out_ppos, float* __restrict__ out_dip,
        float* __restrict__ out_vol) {
    __shared__ float cs[4][256];
    __shared__ float xs[4][256];
    __shared__ float qs[4][256];
    __shared__ float h1[4][128];
    __shared__ float ps[4][10];
    int tid = threadIdx.x;
    int n0 = blockIdx.x * 4, b = blockIdx.y;
    {
        int h = tid >> 5, d = tid & 31;
        int blk0 = (b * 8 + h) * 2;
        #pragma unroll
        for (int r = 0; r < 4; ++r) {
            int q = n0 + r;
            float l = l_half[blk0 * 64 + q] + l_half[(blk0 + 1) * 64 + q];
            float v0 = o_half[(((size_t)blk0 * 64) + q) * 32 + d];
            float v1 = o_half[(((size_t)(blk0 + 1) * 64) + q) * 32 + d];
            cs[r][tid] = (v0 + v1) / l;
        }
    }
    __syncthreads();
    {
        int c = tid;
        float a[4];
        #pragma unroll
        for (int nn = 0; nn < 4; ++nn) a[nn] = opb[c];
        for (int k = 0; k < 256; ++k) {
            float w = opwT[k * 256 + c];
            #pragma unroll
            for (int nn = 0; nn < 4; ++nn) a[nn] += cs[nn][k] * w;
        }
        #pragma unroll
        for (int nn = 0; nn < 4; ++nn)
            xs[nn][c] = queries[(n0 + nn) * 256 + c] + a[nn];
    }
    __syncthreads();
    {
        int w = tid >> 6, lane = tid & 63;
        int nr = w;
        float x0 = xs[nr][lane], x1 = xs[nr][lane + 64],
              x2 = xs[nr][lane + 128], x3 = xs[nr][lane + 192];
        float s = x0 + x1 + x2 + x3;
        #pragma unroll
        for (int off = 32; off >= 1; off >>= 1) s += __shfl_xor(s, off);
        float mu = s * (1.0f / 256.0f);
        float e0 = x0 - mu, e1 = x1 - mu, e2 = x2 - mu, e3 = x3 - mu;
        float v = e0*e0 + e1*e1 + e2*e2 + e3*e3;
        #pragma unroll
        for (int off = 32; off >= 1; off >>= 1) v += __shfl_xor(v, off);
        float rstd = 1.0f / sqrtf(v * (1.0f / 256.0f) + 1e-5f);
        #pragma unroll
        for (int j = 0; j < 4; ++j) {
            int c = lane + 64 * j;
            qs[nr][c] = (xs[nr][c] - mu) * rstd * lng[c] + lnb[c] + metag[b * 256 + c];
        }
    }
    __syncthreads();
    {
        int c = tid;
        float a[4];
        #pragma unroll
        for (int nn = 0; nn < 4; ++nn) a[nn] = tbv[c];
        for (int k = 0; k < 256; ++k) {
            float w = twT[k * 256 + c];
            #pragma unroll
            for (int nn = 0; nn < 4; ++nn) a[nn] += qs[nn][k] * w;
        }
        #pragma unroll
        for (int nn = 0; nn < 4; ++nn)
            twbf[(size_t)(b * 64 + n0 + nn) * 256 + c] = __float2bfloat16(a[nn]);
    }
    {
        int m = tid & 127, g = tid >> 7;
        float a[2];
        #pragma unroll
        for (int q2 = 0; q2 < 2; ++q2) a[q2] = pb1[m];
        for (int k = 0; k < 256; ++k) {
            float w = pw1T[k * 128 + m];
            #pragma unroll
            for (int q2 = 0; q2 < 2; ++q2) a[q2] += qs[g * 2 + q2][k] * w;
        }
        #pragma unroll
        for (int q2 = 0; q2 < 2; ++q2) h1[g * 2 + q2][m] = gelu_exact(a[q2]);
    }
    __syncthreads();
    if (tid < 40) {
        int nr = tid / 10, j = tid % 10;
        float s = pb2[j];
        for (int m = 0; m < 128; ++m) s += h1[nr][m] * pw2[j * 128 + m];
        ps[nr][j] = s;
    }
    __syncthreads();
    if (tid < 4) {
        int nr = tid;
        int gn = b * 64 + n0 + nr;
        #pragma unroll
        for (int j = 0; j < 3; ++j) {
            float delta = tanhf(ps[nr][j]) * 0.2f;
            out_ppos[gn * 3 + j] = p0a[(n0 + nr) * 3 + j] + delta + hshift[b * 4 + j];
        }
        float d0 = ps[nr][3], d1 = ps[nr][4], d2 = ps[nr][5];
        float dn = fmaxf(sqrtf(d0 * d0 + d1 * d1 + d2 * d2), 1e-6f);
        out_dip[gn * 3 + 0] = d0 / dn;
        out_dip[gn * 3 + 1] = d1 / dn;
        out_dip[gn * 3 + 2] = d2 / dn;
        #pragma unroll
        for (int j = 0; j < 3; ++j)
            out_vol[gn * 3 + j] = sigmoidf_(ps[nr][6 + j]) * 0.5f + 0.001f;
        out_amp[gn] = sigmoidf_(ps[nr][9]) + 0.0001f;
    }
}

// ---------------- temporal logits via MFMA bf16 (double-buffered staging) ----
__global__ __launch_bounds__(256) void k_temporal(
        const float* __restrict__ lf, const short* __restrict__ twbf,
        short* __restrict__ logits) {
    __shared__ __align__(16) short tws[64 * 264];
    __shared__ __align__(16) short lfs[2][32 * 132];
    int tid = threadIdx.x;
    int t0 = blockIdx.x * 128, b = blockIdx.y;
    int wave = tid >> 6, lane = tid & 63;
    int lm = lane & 15, quad = lane >> 4;

    #pragma unroll
    for (int i = 0; i < 8; ++i) {
        int id = i * 256 + tid;
        int n = id >> 5, c8 = id & 31;
        s16x8 v = *(const s16x8*)&twbf[(size_t)(b * 64 + n) * 256 + c8 * 8];
        *(s16x8*)&tws[n * 264 + c8 * 8] = v;
    }

    float4 fr[4];
    // prologue: stage ksi = 0 into lfs[0]
    #pragma unroll
    for (int r = 0; r < 4; ++r) {
        int id = r * 256 + tid;
        int c = id >> 5, t4 = id & 31;
        fr[r] = *(const float4*)&lf[((size_t)(b * 256 + c)) * 4096 + t0 + t4 * 4];
    }
    #pragma unroll
    for (int r = 0; r < 4; ++r) {
        int id = r * 256 + tid;
        int c = id >> 5, t4 = id & 31;
        ushort4 o;
        o.x = (unsigned short)f2bf_s(fr[r].x);
        o.y = (unsigned short)f2bf_s(fr[r].y);
        o.z = (unsigned short)f2bf_s(fr[r].z);
        o.w = (unsigned short)f2bf_s(fr[r].w);
        *(ushort4*)&lfs[0][c * 132 + t4 * 4] = o;
    }

    f32x4 acc[2][4];
    #pragma unroll
    for (int mi = 0; mi < 2; ++mi)
        #pragma unroll
        for (int ni = 0; ni < 4; ++ni) acc[mi][ni] = (f32x4)(0.0f);

    __syncthreads();

    for (int ksi = 0; ksi < 8; ++ksi) {
        int cur = ksi & 1;
        if (ksi < 7) {
            // issue next tile's global loads early (hide under MFMA)
            int c0n = (ksi + 1) * 32;
            #pragma unroll
            for (int r = 0; r < 4; ++r) {
                int id = r * 256 + tid;
                int c = id >> 5, t4 = id & 31;
                fr[r] = *(const float4*)&lf[((size_t)(b * 256 + c0n + c)) * 4096 + t0 + t4 * 4];
            }
        }
        int c0 = ksi * 32;
        #pragma unroll
        for (int mi = 0; mi < 2; ++mi) {
            int tl = wave * 32 + mi * 16 + lm;
            s16x8 af;
            #pragma unroll
            for (int j = 0; j < 8; ++j)
                af[j] = lfs[cur][(quad * 8 + j) * 132 + tl];
            #pragma unroll
            for (int ni = 0; ni < 4; ++ni) {
                s16x8 bfr = *(const s16x8*)&tws[(ni * 16 + lm) * 264 + c0 + quad * 8];
                acc[mi][ni] = __builtin_amdgcn_mfma_f32_16x16x32_bf16(af, bfr, acc[mi][ni], 0, 0, 0);
            }
        }
        if (ksi < 7) {
            #pragma unroll
            for (int r = 0; r < 4; ++r) {
                int id = r * 256 + tid;
                int c = id >> 5, t4 = id & 31;
                ushort4 o;
                o.x = (unsigned short)f2bf_s(fr[r].x);
                o.y = (unsigned short)f2bf_s(fr[r].y);
                o.z = (unsigned short)f2bf_s(fr[r].z);
                o.w = (unsigned short)f2bf_s(fr[r].w);
                *(ushort4*)&lfs[cur ^ 1][c * 132 + t4 * 4] = o;
            }
        }
        __syncthreads();
    }
    #pragma unroll
    for (int mi = 0; mi < 2; ++mi) {
        #pragma unroll
        for (int ni = 0; ni < 4; ++ni) {
            int n = ni * 16 + lm;
            int t = t0 + wave * 32 + mi * 16 + quad * 4;
            ushort4 o;
            o.x = (unsigned short)f2bf_s(acc[mi][ni][0] * 0.0625f);
            o.y = (unsigned short)f2bf_s(acc[mi][ni][1] * 0.0625f);
            o.z = (unsigned short)f2bf_s(acc[mi][ni][2] * 0.0625f);
            o.w = (unsigned short)f2bf_s(acc[mi][ni][3] * 0.0625f);
            *(ushort4*)&logits[(size_t)(b * 64 + n) * 4096 + t] = o;
        }
    }
}

// ---------------- warped sampling + sigmoid envelope (LDS-staged, branchless)
// one block per (b,n): stage 4096 logits + zero pads into LDS, then 16 t/thread.
__global__ __launch_bounds__(256) void k_envelope(
        const short* __restrict__ logits,
        const float* __restrict__ out_amp,
        const float* __restrict__ out_ppos,
        const float* __restrict__ wds,
        const float* __restrict__ ebp,
        float* __restrict__ env) {
    __shared__ __align__(16) short ls[208 + 4096 + 16];
    int bn = blockIdx.x;
    int b = bn >> 6, n = bn & 63;
    int tid = threadIdx.x;
    int lane = tid & 63;
    // zero pads (left 208 for max shift ~205, right 16 for x1 overrun)
    if (tid < 208) ls[tid] = 0;
    if (tid < 16) ls[208 + 4096 + tid] = 0;
    // stage logits row coalesced: 16 shorts per thread
    const short* gl = logits + (size_t)bn * 4096;
    {
        s16x8 v0 = *(const s16x8*)&gl[tid * 16];
        s16x8 v1 = *(const s16x8*)&gl[tid * 16 + 8];
        *(s16x8*)&ls[208 + tid * 16] = v0;
        *(s16x8*)&ls[208 + tid * 16 + 8] = v1;
    }
    // inline delay computation (redundant per wave)
    float v = out_amp[b * 64 + lane];
    int idx = lane;
    #pragma unroll
    for (int off = 1; off < 64; off <<= 1) {
        float ov = __shfl_xor(v, off);
        int oi = __shfl_xor(idx, off);
        if (ov > v || (ov == v && oi < idx)) { v = ov; idx = oi; }
    }
    float dx = out_ppos[(b * 64 + n) * 3 + 0] - out_ppos[(b * 64 + idx) * 3 + 0];
    float dy = out_ppos[(b * 64 + n) * 3 + 1] - out_ppos[(b * 64 + idx) * 3 + 1];
    float dz = out_ppos[(b * 64 + n) * 3 + 2] - out_ppos[(b * 64 + idx) * 3 + 2];
    float dist = sqrtf(dx * dx + dy * dy + dz * dz);
    float sp = log1pf(expf(wds[0]));
    float dl = fminf(fmaxf(sp * dist, 0.f), 0.1f);
    float eb = ebp[0];
    __syncthreads();
    #pragma unroll
    for (int g = 0; g < 4; ++g) {
        int t_base = g * 1024 + tid * 4;
        float ov4[4];
        #pragma unroll
        for (int u = 0; u < 4; ++u) {
            int t = t_base + u;
            float xb = fmaf((float)t, 2.0f / 4095.0f, -1.0f);
            float xp = (xb - dl + 1.0f) * 2047.5f;
            float x0f = floorf(xp);
            int x0 = (int)x0f;
            float w1 = xp - x0f, w0 = 1.0f - w1;
            float g0 = bf2f(ls[208 + x0]);
            float g1 = bf2f(ls[208 + x0 + 1]);
            float sh = w0 * g0 + w1 * g1;
            ov4[u] = 1.0f / (1.0f + __expf(-(sh + eb)));
        }
        float4 o; o.x = ov4[0]; o.y = ov4[1]; o.z = ov4[2]; o.w = ov4[3];
        *reinterpret_cast<float4*>(&env[(size_t)bn * 4096 + t_base]) = o;
    }
}

extern "C" void kernel_launch(void* const* d_in, const int* in_sizes, int n_in,
                              void* d_out, int out_size, void* d_ws, size_t ws_size,
                              hipStream_t stream) {
    const float* lf   = (const float*)d_in[0];
    const float* gf   = (const float*)d_in[1];
    const float* meta = (const float*)d_in[2];
    const float* qrs  = (const float*)d_in[3];
    const float* p0a  = (const float*)d_in[4];
    const float* ipw  = (const float*)d_in[5];
    const float* ipb  = (const float*)d_in[6];
    const float* opw  = (const float*)d_in[7];
    const float* opb  = (const float*)d_in[8];
    const float* lng  = (const float*)d_in[9];
    const float* lnb  = (const float*)d_in[10];
    const float* mw   = (const float*)d_in[11];
    const float* mb   = (const float*)d_in[12];
    const float* twm  = (const float*)d_in[13];
    const float* tbv  = (const float*)d_in[14];
    const float* sw   = (const float*)d_in[15];
    const float* sb   = (const float*)d_in[16];
    const float* pw1  = (const float*)d_in[17];
    const float* pb1  = (const float*)d_in[18];
    const float* pw2  = (const float*)d_in[19];
    const float* pb2  = (const float*)d_in[20];
    const float* wds  = (const float*)d_in[21];
    const float* ebp  = (const float*)d_in[22];

    char* ws = (char*)d_ws;
    short* kvh    = (short*)(ws);                    // 16,777,216  K bf16 [b][t][256]
    short* vTg    = (short*)(ws + 16777216);         // 16,777,216  V^T bf16 [b][n][1024]
    short* logits = (short*)(ws + 50331648);         // 16,777,216  bf16 [b*n][4096]
    float* o_half = (float*)(ws + 67108864);         //  4,194,304
    float* l_half = (float*)(ws + 71303168);         //    131,072
    short* twbf   = (short*)(ws + 71434240);         //  1,048,576
    float* qh     = (float*)(ws + 72482816);         //     65,536
    float* metag  = (float*)(ws + 72581120);         //     32,768
    float* hshift = (float*)(ws + 72613888);         //        512
    float* opwT   = (float*)(ws + 72614400);         //    262,144
    float* twT    = (float*)(ws + 72876544);         //    262,144
    float* pw1T   = (float*)(ws + 73138688);         //    131,072
    short* wkvK   = (short*)(ws + 73269760);         //    131,072
    short* wkvV   = (short*)(ws + 73400832);         //    131,072
    float* partial= (float*)(ws + 73531904);         //    524,288  [b][c][16] mean partials

    float* out_amp  = (float*)d_out;
    float* out_ppos = out_amp + 2048;
    float* out_dip  = out_amp + 8192;
    float* out_vol  = out_amp + 14336;
    float* env      = out_amp + 20480;

    k_prep<<<704, 256, 0, stream>>>(ipw, opw, twm, pw1, qrs, ipb,
                                    opwT, twT, pw1T, (bf16*)wkvK, (bf16*)wkvV, qh);
    k_kv<<<512, 256, 0, stream>>>(gf, wkvK, wkvV, ipb, kvh, vTg, partial);
    k_attn<<<dim3(2, 8, 34), 256, 0, stream>>>(kvh, vTg, qh, meta, mw, mb, partial,
                                               sw, sb, o_half, l_half, metag, hshift);
    k_post<<<dim3(16, 32), 256, 0, stream>>>(o_half, l_half, qrs, opwT, opb, lng, lnb,
                                             metag, hshift, twT, tbv, pw1T, pb1, pw2, pb2,
                                             p0a, (bf16*)twbf, out_amp, out_ppos,
                                             out_dip, out_vol);
    k_temporal<<<dim3(32, 32), 256, 0, stream>>>(lf, twbf, logits);
    k_envelope<<<2048, 256, 0, stream>>>(logits, out_amp, out_ppos, wds, ebp, env);
}

// Round 4
// 359.327 us; speedup vs baseline: 1.1765x; 1.0342x over previous
//
#include <hip/hip_runtime.h>
#include <hip/hip_bf16.h>
#include <math.h>

typedef __hip_bfloat16 bf16;
typedef short s16x8 __attribute__((ext_vector_type(8)));
typedef float f32x4 __attribute__((ext_vector_type(4)));

#define NDIM 256
#define NTG 1024
#define NT 4096

__device__ __forceinline__ float gelu_exact(float x) {
    return 0.5f * x * (1.0f + erff(x * 0.70710678118654752440f));
}
__device__ __forceinline__ float sigmoidf_(float x) {
    return 1.0f / (1.0f + __expf(-x));
}
__device__ __forceinline__ short f2bf_s(float x) {
    union { bf16 h; short s; } cv;
    cv.h = __float2bfloat16(x);
    return cv.s;
}
__device__ __forceinline__ float bf2f(short s) {
    union { bf16 h; short s; } cv;
    cv.s = s;
    return __bfloat162float(cv.h);
}

// ---------------- prep: wkv bf16 cvt only (must precede k_kv) ----------------
__global__ __launch_bounds__(256) void k_prep(
        const float* __restrict__ ipw,
        bf16* __restrict__ wkvK, bf16* __restrict__ wkvV) {
    int id = blockIdx.x * 256 + threadIdx.x;
    wkvK[id] = __float2bfloat16(ipw[65536 + id]);
    wkvV[id] = __float2bfloat16(ipw[131072 + id]);
}

// ---------------- fused gf-stage + K/V projection + transposes + qh ----------
// blocks [0,512): kv (b = blk>>4, tt = blk&15).
// blocks [512,896): weight transposes for k_post (independent work).
// blocks [896,960): qh projection for k_attn.
__global__ __launch_bounds__(256) void k_kv(
        const float* __restrict__ gf, const short* __restrict__ wkvK,
        const short* __restrict__ wkvV, const float* __restrict__ ipb,
        const float* __restrict__ ipw, const float* __restrict__ opw,
        const float* __restrict__ twm, const float* __restrict__ pw1,
        const float* __restrict__ queries,
        short* __restrict__ kvh, short* __restrict__ vTg,
        float* __restrict__ partial,
        float* __restrict__ opwT, float* __restrict__ twT,
        float* __restrict__ pw1T, float* __restrict__ qh) {
    __shared__ __align__(16) short gfs[64 * 264];
    int blk = blockIdx.x, tid = threadIdx.x;
    if (blk >= 512) {
        if (blk < 896) {
            int id = (blk - 512) * 256 + tid;
            if (id < 65536) {
                int k = id >> 8, cc = id & 255;
                opwT[id] = opw[cc * 256 + k];
                twT[id]  = twm[cc * 256 + k];
            } else {
                int id2 = id - 65536;
                int k = id2 >> 7, m = id2 & 127;
                pw1T[id2] = pw1[m * 256 + k];
            }
        } else {
            float* qrow = (float*)gfs;
            int n = blk - 896, cc = tid;
            qrow[cc] = queries[n * 256 + cc];
            __syncthreads();
            float s = ipb[cc];
            const float* wr = ipw + cc * 256;
            for (int k = 0; k < 256; ++k) s += qrow[k] * wr[k];
            qh[n * 256 + cc] = s;
        }
        return;
    }
    int b = blk >> 4, tt = blk & 15;
    int t0 = tt * 64;
    int f4 = tid & 15, grp = tid >> 4;
    // ---- stage + partial sums ----
    #pragma unroll 4
    for (int p = 0; p < 16; ++p) {
        int row = p * 16 + grp;   // channel
        float4 v = *(const float4*)&gf[((size_t)(b * 256 + row)) * 1024 + t0 + f4 * 4];
        gfs[(f4 * 4 + 0) * 264 + row] = f2bf_s(v.x);
        gfs[(f4 * 4 + 1) * 264 + row] = f2bf_s(v.y);
        gfs[(f4 * 4 + 2) * 264 + row] = f2bf_s(v.z);
        gfs[(f4 * 4 + 3) * 264 + row] = f2bf_s(v.w);
        float ps = v.x + v.y + v.z + v.w;
        ps += __shfl_xor(ps, 1); ps += __shfl_xor(ps, 2);
        ps += __shfl_xor(ps, 4); ps += __shfl_xor(ps, 8);
        if (f4 == 0) partial[(b * 256 + row) * 16 + tt] = ps;
    }
    __syncthreads();
    // ---- MFMA phase ----
    int w = tid >> 6, lane = tid & 63, lm = lane & 15, quad = lane >> 4;
    int n0 = w * 64;
    f32x4 acc[4][4];
    // K: acc[ni][mt]
    #pragma unroll
    for (int ni = 0; ni < 4; ++ni)
        #pragma unroll
        for (int mt = 0; mt < 4; ++mt) acc[ni][mt] = (f32x4)(0.0f);
    #pragma unroll
    for (int ks = 0; ks < 8; ++ks) {
        int c = ks * 32 + quad * 8;
        s16x8 gm[4];
        #pragma unroll
        for (int mt = 0; mt < 4; ++mt)
            gm[mt] = *(const s16x8*)&gfs[(mt * 16 + lm) * 264 + c];
        #pragma unroll
        for (int ni = 0; ni < 4; ++ni) {
            s16x8 aw = *(const s16x8*)&wkvK[(n0 + ni * 16 + lm) * 256 + c];
            #pragma unroll
            for (int mt = 0; mt < 4; ++mt)
                acc[ni][mt] = __builtin_amdgcn_mfma_f32_16x16x32_bf16(aw, gm[mt], acc[ni][mt], 0, 0, 0);
        }
    }
    #pragma unroll
    for (int ni = 0; ni < 4; ++ni) {
        int nb4 = n0 + ni * 16 + quad * 4;
        float4 bias = *(const float4*)&ipb[256 + nb4];
        #pragma unroll
        for (int mt = 0; mt < 4; ++mt) {
            int t = t0 + mt * 16 + lm;
            ushort4 o;
            o.x = (unsigned short)f2bf_s(acc[ni][mt][0] + bias.x);
            o.y = (unsigned short)f2bf_s(acc[ni][mt][1] + bias.y);
            o.z = (unsigned short)f2bf_s(acc[ni][mt][2] + bias.z);
            o.w = (unsigned short)f2bf_s(acc[ni][mt][3] + bias.w);
            *(ushort4*)&kvh[((size_t)(b * 1024 + t)) * 256 + nb4] = o;
        }
    }
    // V: acc[mt][ni]
    #pragma unroll
    for (int mt = 0; mt < 4; ++mt)
        #pragma unroll
        for (int ni = 0; ni < 4; ++ni) acc[mt][ni] = (f32x4)(0.0f);
    #pragma unroll
    for (int ks = 0; ks < 8; ++ks) {
        int c = ks * 32 + quad * 8;
        s16x8 gm[4];
        #pragma unroll
        for (int mt = 0; mt < 4; ++mt)
            gm[mt] = *(const s16x8*)&gfs[(mt * 16 + lm) * 264 + c];
        #pragma unroll
        for (int ni = 0; ni < 4; ++ni) {
            s16x8 bw = *(const s16x8*)&wkvV[(n0 + ni * 16 + lm) * 256 + c];
            #pragma unroll
            for (int mt = 0; mt < 4; ++mt)
                acc[mt][ni] = __builtin_amdgcn_mfma_f32_16x16x32_bf16(gm[mt], bw, acc[mt][ni], 0, 0, 0);
        }
    }
    #pragma unroll
    for (int ni = 0; ni < 4; ++ni) {
        int nv = n0 + ni * 16 + lm;
        float bias = ipb[512 + nv];
        #pragma unroll
        for (int mt = 0; mt < 4; ++mt) {
            int t4 = t0 + mt * 16 + quad * 4;
            ushort4 o;
            o.x = (unsigned short)f2bf_s(acc[mt][ni][0] + bias);
            o.y = (unsigned short)f2bf_s(acc[mt][ni][1] + bias);
            o.z = (unsigned short)f2bf_s(acc[mt][ni][2] + bias);
            o.w = (unsigned short)f2bf_s(acc[mt][ni][3] + bias);
            *(ushort4*)&vTg[((size_t)(b * 256 + nv)) * 1024 + t4] = o;
        }
    }
}

// ---------------- MFMA attention (+ metahs on z>=32) -------------------------
// grid (2, 8, 34): z<32 attention; z in {32,33}: metahs for b=(z-32)*16+y*2+x.
__global__ __launch_bounds__(256) void k_attn(
        const short* __restrict__ kvh, const short* __restrict__ vTg,
        const float* __restrict__ qh,
        const float* __restrict__ meta, const float* __restrict__ mw,
        const float* __restrict__ mb, const float* __restrict__ partial,
        const float* __restrict__ sw, const float* __restrict__ sb,
        float* __restrict__ o_half, float* __restrict__ l_half,
        float* __restrict__ metag, float* __restrict__ hshift) {
    __shared__ short pT[4][64 * 40];
    __shared__ float obuf[4][64 * 36];
    __shared__ float lbuf[4 * 64];
    if (blockIdx.z >= 32) {
        int b = (blockIdx.z - 32) * 16 + blockIdx.y * 2 + blockIdx.x;
        int c = threadIdx.x;
        float m = 0.f;
        const float* pp = partial + (b * 256 + c) * 16;
        #pragma unroll
        for (int t = 0; t < 16; ++t) m += pp[t];
        lbuf[c] = m * (1.0f / 1024.0f);
        float s = mb[c];
        #pragma unroll
        for (int j = 0; j < 6; ++j) s += meta[b * 6 + j] * mw[c * 6 + j];
        metag[b * 256 + c] = gelu_exact(s);
        __syncthreads();
        if (c < 3) {
            float t = sb[c];
            for (int k = 0; k < 256; ++k) t += lbuf[k] * sw[c * 256 + k];
            hshift[b * 4 + c] = tanhf(t) * 0.3f;
        }
        return;
    }
    int tid = threadIdx.x;
    int w = tid >> 6, lane = tid & 63, lm = lane & 15, quad = lane >> 4;
    int half = blockIdx.x, h = blockIdx.y, b = blockIdx.z;
    s16x8 aq[4];
    #pragma unroll
    for (int mt = 0; mt < 4; ++mt) {
        const float4* qp = (const float4*)(qh + (mt * 16 + lm) * 256 + h * 32 + quad * 8);
        float4 qa = qp[0], qb = qp[1];
        aq[mt][0] = f2bf_s(qa.x); aq[mt][1] = f2bf_s(qa.y);
        aq[mt][2] = f2bf_s(qa.z); aq[mt][3] = f2bf_s(qa.w);
        aq[mt][4] = f2bf_s(qb.x); aq[mt][5] = f2bf_s(qb.y);
        aq[mt][6] = f2bf_s(qb.z); aq[mt][7] = f2bf_s(qb.w);
    }
    f32x4 acco[2][4];
    #pragma unroll
    for (int dt = 0; dt < 2; ++dt)
        #pragma unroll
        for (int qt = 0; qt < 4; ++qt) acco[dt][qt] = (f32x4)(0.0f);
    float lp[4][4];
    #pragma unroll
    for (int mt = 0; mt < 4; ++mt)
        #pragma unroll
        for (int r = 0; r < 4; ++r) lp[mt][r] = 0.f;
    const float scale = 0.17677669529663687f;   // 1/sqrt(32)
    int kb = half * 512 + w * 128;
    for (int ch = 0; ch < 4; ++ch) {
        int n0 = kb + ch * 32;
        #pragma unroll
        for (int nt = 0; nt < 2; ++nt) {
            int key = n0 + nt * 16 + lm;
            s16x8 bk = *(const s16x8*)&kvh[((size_t)(b * 1024 + key)) * 256 + h * 32 + quad * 8];
            f32x4 zero = {0.f, 0.f, 0.f, 0.f};
            #pragma unroll
            for (int mt = 0; mt < 4; ++mt) {
                f32x4 S = __builtin_amdgcn_mfma_f32_16x16x32_bf16(aq[mt], bk, zero, 0, 0, 0);
                #pragma unroll
                for (int r = 0; r < 4; ++r) {
                    float e = __expf(S[r] * scale);
                    lp[mt][r] += e;
                    pT[w][(mt * 16 + quad * 4 + r) * 40 + nt * 16 + lm] = f2bf_s(e);
                }
            }
        }
        s16x8 av[2], bp[4];
        #pragma unroll
        for (int dt = 0; dt < 2; ++dt)
            av[dt] = *(const s16x8*)&vTg[((size_t)(b * 256 + h * 32 + dt * 16 + lm)) * 1024 + n0 + quad * 8];
        #pragma unroll
        for (int qt = 0; qt < 4; ++qt)
            bp[qt] = *(const s16x8*)&pT[w][(qt * 16 + lm) * 40 + quad * 8];
        #pragma unroll
        for (int dt = 0; dt < 2; ++dt)
            #pragma unroll
            for (int qt = 0; qt < 4; ++qt)
                acco[dt][qt] = __builtin_amdgcn_mfma_f32_16x16x32_bf16(av[dt], bp[qt], acco[dt][qt], 0, 0, 0);
    }
    #pragma unroll
    for (int mt = 0; mt < 4; ++mt)
        #pragma unroll
        for (int r = 0; r < 4; ++r) {
            float v = lp[mt][r];
            v += __shfl_xor(v, 1); v += __shfl_xor(v, 2);
            v += __shfl_xor(v, 4); v += __shfl_xor(v, 8);
            lp[mt][r] = v;
        }
    #pragma unroll
    for (int dt = 0; dt < 2; ++dt)
        #pragma unroll
        for (int qt = 0; qt < 4; ++qt) {
            int q = qt * 16 + lm;
            float4 t;
            t.x = acco[dt][qt][0]; t.y = acco[dt][qt][1];
            t.z = acco[dt][qt][2]; t.w = acco[dt][qt][3];
            *(float4*)&obuf[w][q * 36 + dt * 16 + quad * 4] = t;
        }
    if (lm == 0) {
        #pragma unroll
        for (int mt = 0; mt < 4; ++mt)
            #pragma unroll
            for (int r = 0; r < 4; ++r)
                lbuf[w * 64 + mt * 16 + quad * 4 + r] = lp[mt][r];
    }
    __syncthreads();
    int q = tid & 63, dg = tid >> 6;
    int blk = (b * 8 + h) * 2 + half;
    float l = lbuf[q] + lbuf[64 + q] + lbuf[128 + q] + lbuf[192 + q];
    float o[8];
    #pragma unroll
    for (int j = 0; j < 8; ++j) o[j] = 0.f;
    #pragma unroll
    for (int w2 = 0; w2 < 4; ++w2) {
        const float* src = &obuf[w2][q * 36 + dg * 8];
        #pragma unroll
        for (int j = 0; j < 8; ++j) o[j] += src[j];
    }
    float* dst = &o_half[(((size_t)blk * 64) + q) * 32 + dg * 8];
    #pragma unroll
    for (int j = 0; j < 8; ++j) dst[j] = o[j];
    if (dg == 0) l_half[blk * 64 + q] = l;
}

// ---------------- out_proj + LN + meta + tw(bf16) + phase MLP + geometry -----
// 8 queries per block, 512 threads, grid (8, 32): k-split GEMVs — each weight
// element read ONCE per block (halves L2 traffic), 128-trip loops, 8 FMA/load.
__global__ __launch_bounds__(512) void k_post(
        const float* __restrict__ o_half, const float* __restrict__ l_half,
        const float* __restrict__ queries,
        const float* __restrict__ opwT, const float* __restrict__ opb,
        const float* __restrict__ lng, const float* __restrict__ lnb,
        const float* __restrict__ metag, const float* __restrict__ hshift,
        const float* __restrict__ twT, const float* __restrict__ tbv,
        const float* __restrict__ pw1T, const float* __restrict__ pb1,
        const float* __restrict__ pw2, const float* __restrict__ pb2,
        const float* __restrict__ p0a,
        bf16* __restrict__ twbf, float* __restrict__ out_amp,
        float* __restrict__ out_ppos, float* __restrict__ out_dip,
        float* __restrict__ out_vol) {
    __shared__ float cs[8][256];
    __shared__ float xs[8][256];
    __shared__ float qs[8][256];
    __shared__ float pbuf[2][8][256];
    __shared__ float h1[8][128];
    __shared__ float ps[8][10];
    int tid = threadIdx.x;
    int n0 = blockIdx.x * 8, b = blockIdx.y;
    int rr = tid >> 8, c = tid & 255;
    // A: ctx merge (thread (rr,c) covers rows rr*4..rr*4+3)
    {
        int h = c >> 5, d = c & 31;
        int blk0 = (b * 8 + h) * 2;
        #pragma unroll
        for (int i = 0; i < 4; ++i) {
            int r = rr * 4 + i;
            int q = n0 + r;
            float l = l_half[blk0 * 64 + q] + l_half[(blk0 + 1) * 64 + q];
            float v0 = o_half[(((size_t)blk0 * 64) + q) * 32 + d];
            float v1 = o_half[(((size_t)(blk0 + 1) * 64) + q) * 32 + d];
            cs[r][c] = (v0 + v1) / l;
        }
    }
    __syncthreads();
    // B: out_proj, k-split halves
    {
        float a[8];
        #pragma unroll
        for (int nn = 0; nn < 8; ++nn) a[nn] = 0.f;
        int k0 = rr * 128;
        for (int k = k0; k < k0 + 128; ++k) {
            float w = opwT[k * 256 + c];
            #pragma unroll
            for (int nn = 0; nn < 8; ++nn) a[nn] += cs[nn][k] * w;
        }
        #pragma unroll
        for (int nn = 0; nn < 8; ++nn) pbuf[rr][nn][c] = a[nn];
    }
    __syncthreads();
    {
        #pragma unroll
        for (int i = 0; i < 4; ++i) {
            int nn = rr * 4 + i;
            xs[nn][c] = queries[(n0 + nn) * 256 + c] + opb[c]
                      + pbuf[0][nn][c] + pbuf[1][nn][c];
        }
    }
    __syncthreads();
    // C: LN — 8 waves, wave w owns row w
    {
        int w = tid >> 6, lane = tid & 63;
        float x0 = xs[w][lane], x1 = xs[w][lane + 64],
              x2 = xs[w][lane + 128], x3 = xs[w][lane + 192];
        float s = x0 + x1 + x2 + x3;
        #pragma unroll
        for (int off = 32; off >= 1; off >>= 1) s += __shfl_xor(s, off);
        float mu = s * (1.0f / 256.0f);
        float e0 = x0 - mu, e1 = x1 - mu, e2 = x2 - mu, e3 = x3 - mu;
        float v = e0*e0 + e1*e1 + e2*e2 + e3*e3;
        #pragma unroll
        for (int off = 32; off >= 1; off >>= 1) v += __shfl_xor(v, off);
        float rstd = 1.0f / sqrtf(v * (1.0f / 256.0f) + 1e-5f);
        #pragma unroll
        for (int j = 0; j < 4; ++j) {
            int cc = lane + 64 * j;
            qs[w][cc] = (xs[w][cc] - mu) * rstd * lng[cc] + lnb[cc] + metag[b * 256 + cc];
        }
    }
    __syncthreads();
    // D: temporal weights, k-split
    {
        float a[8];
        #pragma unroll
        for (int nn = 0; nn < 8; ++nn) a[nn] = 0.f;
        int k0 = rr * 128;
        for (int k = k0; k < k0 + 128; ++k) {
            float w = twT[k * 256 + c];
            #pragma unroll
            for (int nn = 0; nn < 8; ++nn) a[nn] += qs[nn][k] * w;
        }
        #pragma unroll
        for (int nn = 0; nn < 8; ++nn) pbuf[rr][nn][c] = a[nn];
    }
    __syncthreads();
    {
        #pragma unroll
        for (int i = 0; i < 4; ++i) {
            int nn = rr * 4 + i;
            twbf[(size_t)(b * 64 + n0 + nn) * 256 + c] =
                __float2bfloat16(tbv[c] + pbuf[0][nn][c] + pbuf[1][nn][c]);
        }
    }
    __syncthreads();   // pbuf reuse barrier
    // E: phase MLP layer1, k-split + q-quad split
    {
        int m = tid & 127, qq = (tid >> 7) & 1;
        float a[4];
        #pragma unroll
        for (int i = 0; i < 4; ++i) a[i] = 0.f;
        int k0 = rr * 128;
        for (int k = k0; k < k0 + 128; ++k) {
            float w = pw1T[k * 128 + m];
            #pragma unroll
            for (int i = 0; i < 4; ++i) a[i] += qs[qq * 4 + i][k] * w;
        }
        #pragma unroll
        for (int i = 0; i < 4; ++i) pbuf[rr][qq * 4 + i][m] = a[i];
    }
    __syncthreads();
    {
        #pragma unroll
        for (int u = 0; u < 2; ++u) {
            int id = u * 512 + tid;
            int nr = id >> 7, m = id & 127;
            h1[nr][m] = gelu_exact(pb1[m] + pbuf[0][nr][m] + pbuf[1][nr][m]);
        }
    }
    __syncthreads();
    if (tid < 80) {
        int nr = tid / 10, j = tid % 10;
        float s = pb2[j];
        for (int m = 0; m < 128; ++m) s += h1[nr][m] * pw2[j * 128 + m];
        ps[nr][j] = s;
    }
    __syncthreads();
    if (tid < 8) {
        int nr = tid;
        int gn = b * 64 + n0 + nr;
        #pragma unroll
        for (int j = 0; j < 3; ++j) {
            float delta = tanhf(ps[nr][j]) * 0.2f;
            out_ppos[gn * 3 + j] = p0a[(n0 + nr) * 3 + j] + delta + hshift[b * 4 + j];
        }
        float d0 = ps[nr][3], d1 = ps[nr][4], d2 = ps[nr][5];
        float dn = fmaxf(sqrtf(d0 * d0 + d1 * d1 + d2 * d2), 1e-6f);
        out_dip[gn * 3 + 0] = d0 / dn;
        out_dip[gn * 3 + 1] = d1 / dn;
        out_dip[gn * 3 + 2] = d2 / dn;
        #pragma unroll
        for (int j = 0; j < 3; ++j)
            out_vol[gn * 3 + j] = sigmoidf_(ps[nr][6 + j]) * 0.5f + 0.001f;
        out_amp[gn] = sigmoidf_(ps[nr][9]) + 0.0001f;
    }
}

// ---------------- temporal logits via MFMA bf16 (double-buffered staging) ----
__global__ __launch_bounds__(256) void k_temporal(
        const float* __restrict__ lf, const short* __restrict__ twbf,
        short* __restrict__ logits) {
    __shared__ __align__(16) short tws[64 * 264];
    __shared__ __align__(16) short lfs[2][32 * 132];
    int tid = threadIdx.x;
    int t0 = blockIdx.x * 128, b = blockIdx.y;
    int wave = tid >> 6, lane = tid & 63;
    int lm = lane & 15, quad = lane >> 4;

    #pragma unroll
    for (int i = 0; i < 8; ++i) {
        int id = i * 256 + tid;
        int n = id >> 5, c8 = id & 31;
        s16x8 v = *(const s16x8*)&twbf[(size_t)(b * 64 + n) * 256 + c8 * 8];
        *(s16x8*)&tws[n * 264 + c8 * 8] = v;
    }

    float4 fr[4];
    // prologue: stage ksi = 0 into lfs[0]
    #pragma unroll
    for (int r = 0; r < 4; ++r) {
        int id = r * 256 + tid;
        int c = id >> 5, t4 = id & 31;
        fr[r] = *(const float4*)&lf[((size_t)(b * 256 + c)) * 4096 + t0 + t4 * 4];
    }
    #pragma unroll
    for (int r = 0; r < 4; ++r) {
        int id = r * 256 + tid;
        int c = id >> 5, t4 = id & 31;
        ushort4 o;
        o.x = (unsigned short)f2bf_s(fr[r].x);
        o.y = (unsigned short)f2bf_s(fr[r].y);
        o.z = (unsigned short)f2bf_s(fr[r].z);
        o.w = (unsigned short)f2bf_s(fr[r].w);
        *(ushort4*)&lfs[0][c * 132 + t4 * 4] = o;
    }

    f32x4 acc[2][4];
    #pragma unroll
    for (int mi = 0; mi < 2; ++mi)
        #pragma unroll
        for (int ni = 0; ni < 4; ++ni) acc[mi][ni] = (f32x4)(0.0f);

    __syncthreads();

    for (int ksi = 0; ksi < 8; ++ksi) {
        int cur = ksi & 1;
        if (ksi < 7) {
            // issue next tile's global loads early (hide under MFMA)
            int c0n = (ksi + 1) * 32;
            #pragma unroll
            for (int r = 0; r < 4; ++r) {
                int id = r * 256 + tid;
                int c = id >> 5, t4 = id & 31;
                fr[r] = *(const float4*)&lf[((size_t)(b * 256 + c0n + c)) * 4096 + t0 + t4 * 4];
            }
        }
        int c0 = ksi * 32;
        #pragma unroll
        for (int mi = 0; mi < 2; ++mi) {
            int tl = wave * 32 + mi * 16 + lm;
            s16x8 af;
            #pragma unroll
            for (int j = 0; j < 8; ++j)
                af[j] = lfs[cur][(quad * 8 + j) * 132 + tl];
            #pragma unroll
            for (int ni = 0; ni < 4; ++ni) {
                s16x8 bfr = *(const s16x8*)&tws[(ni * 16 + lm) * 264 + c0 + quad * 8];
                acc[mi][ni] = __builtin_amdgcn_mfma_f32_16x16x32_bf16(af, bfr, acc[mi][ni], 0, 0, 0);
            }
        }
        if (ksi < 7) {
            #pragma unroll
            for (int r = 0; r < 4; ++r) {
                int id = r * 256 + tid;
                int c = id >> 5, t4 = id & 31;
                ushort4 o;
                o.x = (unsigned short)f2bf_s(fr[r].x);
                o.y = (unsigned short)f2bf_s(fr[r].y);
                o.z = (unsigned short)f2bf_s(fr[r].z);
                o.w = (unsigned short)f2bf_s(fr[r].w);
                *(ushort4*)&lfs[cur ^ 1][c * 132 + t4 * 4] = o;
            }
        }
        __syncthreads();
    }
    #pragma unroll
    for (int mi = 0; mi < 2; ++mi) {
        #pragma unroll
        for (int ni = 0; ni < 4; ++ni) {
            int n = ni * 16 + lm;
            int t = t0 + wave * 32 + mi * 16 + quad * 4;
            ushort4 o;
            o.x = (unsigned short)f2bf_s(acc[mi][ni][0] * 0.0625f);
            o.y = (unsigned short)f2bf_s(acc[mi][ni][1] * 0.0625f);
            o.z = (unsigned short)f2bf_s(acc[mi][ni][2] * 0.0625f);
            o.w = (unsigned short)f2bf_s(acc[mi][ni][3] * 0.0625f);
            *(ushort4*)&logits[(size_t)(b * 64 + n) * 4096 + t] = o;
        }
    }
}

// ---------------- warped sampling + sigmoid envelope (LDS-staged, branchless)
// one block per (b,n): stage 4096 logits + zero pads into LDS, then 16 t/thread.
__global__ __launch_bounds__(256) void k_envelope(
        const short* __restrict__ logits,
        const float* __restrict__ out_amp,
        const float* __restrict__ out_ppos,
        const float* __restrict__ wds,
        const float* __restrict__ ebp,
        float* __restrict__ env) {
    __shared__ __align__(16) short ls[208 + 4096 + 16];
    int bn = blockIdx.x;
    int b = bn >> 6, n = bn & 63;
    int tid = threadIdx.x;
    int lane = tid & 63;
    // zero pads (left 208 for max shift ~205, right 16 for x1 overrun)
    if (tid < 208) ls[tid] = 0;
    if (tid < 16) ls[208 + 4096 + tid] = 0;
    // stage logits row coalesced: 16 shorts per thread
    const short* gl = logits + (size_t)bn * 4096;
    {
        s16x8 v0 = *(const s16x8*)&gl[tid * 16];
        s16x8 v1 = *(const s16x8*)&gl[tid * 16 + 8];
        *(s16x8*)&ls[208 + tid * 16] = v0;
        *(s16x8*)&ls[208 + tid * 16 + 8] = v1;
    }
    // inline delay computation (redundant per wave)
    float v = out_amp[b * 64 + lane];
    int idx = lane;
    #pragma unroll
    for (int off = 1; off < 64; off <<= 1) {
        float ov = __shfl_xor(v, off);
        int oi = __shfl_xor(idx, off);
        if (ov > v || (ov == v && oi < idx)) { v = ov; idx = oi; }
    }
    float dx = out_ppos[(b * 64 + n) * 3 + 0] - out_ppos[(b * 64 + idx) * 3 + 0];
    float dy = out_ppos[(b * 64 + n) * 3 + 1] - out_ppos[(b * 64 + idx) * 3 + 1];
    float dz = out_ppos[(b * 64 + n) * 3 + 2] - out_ppos[(b * 64 + idx) * 3 + 2];
    float dist = sqrtf(dx * dx + dy * dy + dz * dz);
    float sp = log1pf(expf(wds[0]));
    float dl = fminf(fmaxf(sp * dist, 0.f), 0.1f);
    float eb = ebp[0];
    __syncthreads();
    #pragma unroll
    for (int g = 0; g < 4; ++g) {
        int t_base = g * 1024 + tid * 4;
        float ov4[4];
        #pragma unroll
        for (int u = 0; u < 4; ++u) {
            int t = t_base + u;
            float xb = fmaf((float)t, 2.0f / 4095.0f, -1.0f);
            float xp = (xb - dl + 1.0f) * 2047.5f;
            float x0f = floorf(xp);
            int x0 = (int)x0f;
            float w1 = xp - x0f, w0 = 1.0f - w1;
            float g0 = bf2f(ls[208 + x0]);
            float g1 = bf2f(ls[208 + x0 + 1]);
            float sh = w0 * g0 + w1 * g1;
            ov4[u] = 1.0f / (1.0f + __expf(-(sh + eb)));
        }
        float4 o; o.x = ov4[0]; o.y = ov4[1]; o.z = ov4[2]; o.w = ov4[3];
        *reinterpret_cast<float4*>(&env[(size_t)bn * 4096 + t_base]) = o;
    }
}

extern "C" void kernel_launch(void* const* d_in, const int* in_sizes, int n_in,
                              void* d_out, int out_size, void* d_ws, size_t ws_size,
                              hipStream_t stream) {
    const float* lf   = (const float*)d_in[0];
    const float* gf   = (const float*)d_in[1];
    const float* meta = (const float*)d_in[2];
    const float* qrs  = (const float*)d_in[3];
    const float* p0a  = (const float*)d_in[4];
    const float* ipw  = (const float*)d_in[5];
    const float* ipb  = (const float*)d_in[6];
    const float* opw  = (const float*)d_in[7];
    const float* opb  = (const float*)d_in[8];
    const float* lng  = (const float*)d_in[9];
    const float* lnb  = (const float*)d_in[10];
    const float* mw   = (const float*)d_in[11];
    const float* mb   = (const float*)d_in[12];
    const float* twm  = (const float*)d_in[13];
    const float* tbv  = (const float*)d_in[14];
    const float* sw   = (const float*)d_in[15];
    const float* sb   = (const float*)d_in[16];
    const float* pw1  = (const float*)d_in[17];
    const float* pb1  = (const float*)d_in[18];
    const float* pw2  = (const float*)d_in[19];
    const float* pb2  = (const float*)d_in[20];
    const float* wds  = (const float*)d_in[21];
    const float* ebp  = (const float*)d_in[22];

    char* ws = (char*)d_ws;
    short* kvh    = (short*)(ws);                    // 16,777,216  K bf16 [b][t][256]
    short* vTg    = (short*)(ws + 16777216);         // 16,777,216  V^T bf16 [b][n][1024]
    short* logits = (short*)(ws + 50331648);         // 16,777,216  bf16 [b*n][4096]
    float* o_half = (float*)(ws + 67108864);         //  4,194,304
    float* l_half = (float*)(ws + 71303168);         //    131,072
    short* twbf   = (short*)(ws + 71434240);         //  1,048,576
    float* qh     = (float*)(ws + 72482816);         //     65,536
    float* metag  = (float*)(ws + 72581120);         //     32,768
    float* hshift = (float*)(ws + 72613888);         //        512
    float* opwT   = (float*)(ws + 72614400);         //    262,144
    float* twT    = (float*)(ws + 72876544);         //    262,144
    float* pw1T   = (float*)(ws + 73138688);         //    131,072
    short* wkvK   = (short*)(ws + 73269760);         //    131,072
    short* wkvV   = (short*)(ws + 73400832);         //    131,072
    float* partial= (float*)(ws + 73531904);         //    524,288  [b][c][16] mean partials

    float* out_amp  = (float*)d_out;
    float* out_ppos = out_amp + 2048;
    float* out_dip  = out_amp + 8192;
    float* out_vol  = out_amp + 14336;
    float* env      = out_amp + 20480;

    k_prep<<<256, 256, 0, stream>>>(ipw, (bf16*)wkvK, (bf16*)wkvV);
    k_kv<<<960, 256, 0, stream>>>(gf, wkvK, wkvV, ipb, ipw, opw, twm, pw1, qrs,
                                  kvh, vTg, partial, opwT, twT, pw1T, qh);
    k_attn<<<dim3(2, 8, 34), 256, 0, stream>>>(kvh, vTg, qh, meta, mw, mb, partial,
                                               sw, sb, o_half, l_half, metag, hshift);
    k_post<<<dim3(8, 32), 512, 0, stream>>>(o_half, l_half, qrs, opwT, opb, lng, lnb,
                                            metag, hshift, twT, tbv, pw1T, pb1, pw2, pb2,
                                            p0a, (bf16*)twbf, out_amp, out_ppos,
                                            out_dip, out_vol);
    k_temporal<<<dim3(32, 32), 256, 0, stream>>>(lf, twbf, logits);
    k_envelope<<<2048, 256, 0, stream>>>(logits, out_amp, out_ppos, wds, ebp, env);
}